// Round 18
// baseline (243.400 us; speedup 1.0000x reference)
//
#include <hip/hip_runtime.h>

// ---------------------------------------------------------------------------
// 2-layer GCN forward (PyG GCNConv, add_self_loops, sym-norm), CSR-gather.
//   dinv = rsqrt(segsum(ew,dst)+1)
//   h    = relu( Agg(norm, x@W1) + dinv^2*(x@W1) + b1 )
//   out  = L2norm( Agg(norm, h@W2) + dinv^2*(h@W2) + b2 )
// CSR build = LDS counting sort (NO global atomics; 74us atomic cap R6-R9).
// Schedule: count -> s2a/s2b -> FAT(gemm1 || s3 scatter) -> s4.
// NSLAB=640 (R16's 384 unbalanced the fat co-schedule: fat 80->89).
// s2a = tiled transpose-scan (coalesced 64B strips; old version was 1M
// stride-3128B scalar transactions).
// GEMM1: single-pass bf16 W; register-prefetch pipeline + LDS-bounce epilogue.
// agg1 bf16. tmp packed 8B (src|lid|fix22). hw2 64-col bf16 pre-scaled.
// ---------------------------------------------------------------------------

typedef unsigned short u16;
typedef unsigned long long u64;
typedef __attribute__((ext_vector_type(8))) short short8;
typedef __attribute__((ext_vector_type(4))) float f32x4;

#define FIXSCALE 4194304.0f   // 2^22 fixed-point for deterministic deg
#define HW2S 64               // hw2 row stride (bf16), 40 real + 24 zero pad
#define NSLAB 640             // sort slabs (count/s3 blocks)
#define MAXBUCK 832           // LDS capacity for bucket counters (>= NBUCK)
#define SB 16                 // buckets per s2a block

static __device__ inline u16 f2bf(float f) {            // RNE f32 -> bf16 bits
    unsigned u = __float_as_uint(f);
    return (u16)((u + 0x7fffu + ((u >> 16) & 1u)) >> 16);
}
static __device__ inline float bf2f(u16 h) { return __uint_as_float(((unsigned)h) << 16); }

// pass 1: per-slab bucket histogram (LDS atomics only)
__launch_bounds__(256)
__global__ void k_count(const int* __restrict__ dst, int* __restrict__ cnt1,
                        int E, int EPB, int NBUCK) {
    __shared__ int cnt[MAXBUCK];
    int b = blockIdx.x;
    for (int j = threadIdx.x; j < NBUCK; j += 256) cnt[j] = 0;
    __syncthreads();
    int beg = b * EPB, end = min(beg + EPB, E);
    for (int i = beg + threadIdx.x; i < end; i += 256)
        atomicAdd(&cnt[dst[i] >> 7], 1);
    __syncthreads();
    for (int j = threadIdx.x; j < NBUCK; j += 256)
        cnt1[(size_t)b * NBUCK + j] = cnt[j];
}

// pass 2a (tiled): 16 buckets/block; coalesced 64B strip loads; serial
// column scan in LDS; coalesced writeback. Exclusive scan over slabs.
__launch_bounds__(256)
__global__ void k_s2a(int* __restrict__ cnt1, int* __restrict__ colTot, int NBUCK) {
    __shared__ int d[NSLAB][SB + 1];
    int j0 = blockIdx.x * SB;
    int nj = min(SB, NBUCK - j0);
    int t = threadIdx.x;
    for (int f = t; f < NSLAB * SB; f += 256) {
        int b = f >> 4, jj = f & 15;
        d[b][jj] = (jj < nj) ? cnt1[(size_t)b * NBUCK + j0 + jj] : 0;
    }
    __syncthreads();
    if (t < SB) {
        int run = 0;
        for (int b = 0; b < NSLAB; ++b) {
            int v = d[b][t];
            d[b][t] = run;
            run += v;
        }
        if (t < nj) colTot[j0 + t] = run;
    }
    __syncthreads();
    for (int f = t; f < NSLAB * SB; f += 256) {
        int b = f >> 4, jj = f & 15;
        if (jj < nj) cnt1[(size_t)b * NBUCK + j0 + jj] = d[b][jj];
    }
}

// pass 2b: scan bucket totals -> bucketBase; rowp[N]=E
__launch_bounds__(1024)
__global__ void k_s2b(const int* __restrict__ colTot, int* __restrict__ bucketBase,
                      int* __restrict__ rowp, int NBUCK, int N, int E) {
    __shared__ int s[1024];
    int t = threadIdx.x;
    int v = (t < NBUCK) ? colTot[t] : 0;
    s[t] = v;
    __syncthreads();
    for (int off = 1; off < 1024; off <<= 1) {
        int u = (t >= off) ? s[t - off] : 0;
        __syncthreads();
        s[t] += u;
        __syncthreads();
    }
    if (t < NBUCK) bucketBase[t] = s[t] - v;
    if (t == NBUCK - 1) bucketBase[NBUCK] = s[t];
    if (t == 0) rowp[N] = E;
}

// ---- FAT kernel: [0,gB) gemm1 tiles; [gB,gB+NSLAB) s3 scatter slabs -------
__launch_bounds__(256)
__global__ void k_fat(const float* __restrict__ x, const u16* __restrict__ wt_hi,
                      u16* __restrict__ xw1, int N,
                      const int* __restrict__ src, const int* __restrict__ dst,
                      const float* __restrict__ ew, const int* __restrict__ cnt1,
                      const int* __restrict__ bucketBase, u64* __restrict__ tmp,
                      int E, int gB, int EPB, int NBUCK) {
    __shared__ __align__(16) u16 S[10240];   // 20KB: Ah | Bh, reused by epilogue/s3
    u16* Ah = S;
    u16* Bh = S + 5120;

    if (blockIdx.x >= gB) {
        // ---- s3: scatter packed records to bucket-major tmp (LDS cursors) --
        int* ldsOff = (int*)S;
        int b = blockIdx.x - gB, t = threadIdx.x;
        for (int j = t; j < NBUCK; j += 256)
            ldsOff[j] = bucketBase[j] + cnt1[(size_t)b * NBUCK + j];
        __syncthreads();
        int beg = b * EPB, end = min(beg + EPB, E);
        for (int i = beg + t; i < end; i += 256) {
            int d = dst[i];
            int slot = atomicAdd(&ldsOff[d >> 7], 1);
            unsigned fix = (unsigned)__float2uint_rn(ew[i] * FIXSCALE);  // <= 2^22
            tmp[slot] = ((u64)(unsigned)src[i] << 30) | ((u64)(d & 127) << 23) | fix;
        }
        return;
    }

    // ------- gemm1: MFMA, LDS-staged, register-prefetch pipeline ----------
    const int t = threadIdx.x;
    const int w = t >> 6;
    const int lane = t & 63;
    const int lrow = lane & 15;
    const int q = lane >> 4;
    const int lk = q * 8;
    const int row0 = blockIdx.x * 128;

    int rA[4], cA[4];
    const float* pA[4];
    bool okA[4];
#pragma unroll
    for (int i = 0; i < 4; ++i) {
        int flat = t + i * 256;
        rA[i] = flat >> 3;
        cA[i] = flat & 7;
        int gr = row0 + rA[i];
        okA[i] = gr < N;
        pA[i] = x + (size_t)min(gr, N - 1) * 256 + cA[i] * 4;
    }
    int nB[2], cB[2];
    const u16* pB[2];
#pragma unroll
    for (int i = 0; i < 2; ++i) {
        int flat = t + i * 256;
        nB[i] = flat >> 2;
        cB[i] = flat & 3;
        pB[i] = wt_hi + (size_t)nB[i] * 256 + cB[i] * 8;
    }

    float4 ra[4];
    short8 rb[2];
#pragma unroll
    for (int i = 0; i < 4; ++i)
        ra[i] = okA[i] ? *(const float4*)(pA[i]) : make_float4(0.f, 0.f, 0.f, 0.f);
#pragma unroll
    for (int i = 0; i < 2; ++i) rb[i] = *(const short8*)(pB[i]);

    f32x4 acc[2][8] = {};

    for (int kt = 0; kt < 8; ++kt) {
#pragma unroll
        for (int i = 0; i < 4; ++i) {
            ushort4 vh;
            vh.x = f2bf(ra[i].x);
            vh.y = f2bf(ra[i].y);
            vh.z = f2bf(ra[i].z);
            vh.w = f2bf(ra[i].w);
            *(ushort4*)(Ah + rA[i] * 40 + cA[i] * 4) = vh;
        }
#pragma unroll
        for (int i = 0; i < 2; ++i)
            *(short8*)(Bh + nB[i] * 40 + cB[i] * 8) = rb[i];
        __syncthreads();

        if (kt < 7) {
#pragma unroll
            for (int i = 0; i < 4; ++i)
                ra[i] = okA[i] ? *(const float4*)(pA[i] + (kt + 1) * 32)
                               : make_float4(0.f, 0.f, 0.f, 0.f);
#pragma unroll
            for (int i = 0; i < 2; ++i)
                rb[i] = *(const short8*)(pB[i] + (kt + 1) * 32);
        }

        short8 a0 = *(const short8*)(Ah + (w * 32 + lrow) * 40 + lk);
        short8 a1 = *(const short8*)(Ah + (w * 32 + 16 + lrow) * 40 + lk);
#pragma unroll
        for (int ni = 0; ni < 8; ++ni) {
            short8 bh = *(const short8*)(Bh + (ni * 16 + lrow) * 40 + lk);
            acc[0][ni] = __builtin_amdgcn_mfma_f32_16x16x32_bf16(a0, bh, acc[0][ni], 0, 0, 0);
            acc[1][ni] = __builtin_amdgcn_mfma_f32_16x16x32_bf16(a1, bh, acc[1][ni], 0, 0, 0);
        }
        __syncthreads();
    }

    // ---- epilogue: LDS-bounce transpose -> coalesced 16B stores ----------
#pragma unroll
    for (int mi = 0; mi < 2; ++mi) {
        if (mi) __syncthreads();
#pragma unroll
        for (int r = 0; r < 4; ++r)
#pragma unroll
            for (int ni = 0; ni < 8; ++ni)
                S[(w * 16 + q * 4 + r) * 136 + lrow + ni * 16] = f2bf(acc[mi][ni][r]);
        __syncthreads();
        int l = t >> 2;
        int grow = row0 + (l >> 4) * 32 + mi * 16 + (l & 15);
        if (grow < N) {
#pragma unroll
            for (int c = 0; c < 4; ++c) {
                int col = (t & 3) * 8 + c * 32;
                *(short8*)(xw1 + (size_t)grow * 128 + col) =
                    *(const short8*)(S + l * 136 + col);
            }
        }
    }
}

// pass 4: per bucket (128 nodes): counts+deg (LDS), scan -> rowp/dinv,
// then write entries (src, ew*dinv_dst) to final contiguous slots.
__launch_bounds__(256)
__global__ void k_s4(const u64* __restrict__ tmp, const int* __restrict__ bucketBase,
                     int* __restrict__ rowp, float* __restrict__ dinv,
                     int2* __restrict__ entries, int N) {
    __shared__ int cnt[128];
    __shared__ unsigned degfix[128];
    __shared__ int sc[128];
    __shared__ int nextOff[128];
    __shared__ float dl[128];
    int k = blockIdx.x, t = threadIdx.x;
    int base = bucketBase[k], endb = bucketBase[k + 1];
    if (t < 128) { cnt[t] = 0; degfix[t] = 0; }
    __syncthreads();
    for (int i = base + t; i < endb; i += 256) {
        u64 r = tmp[i];
        int lid = (int)(r >> 23) & 127;
        atomicAdd(&cnt[lid], 1);
        atomicAdd(&degfix[lid], (unsigned)(r & 0x7fffff));
    }
    __syncthreads();
    if (t < 128) sc[t] = cnt[t];
    __syncthreads();
    for (int off = 1; off < 128; off <<= 1) {
        int u = 0;
        if (t < 128 && t >= off) u = sc[t - off];
        __syncthreads();
        if (t < 128) sc[t] += u;
        __syncthreads();
    }
    if (t < 128) {
        int off0 = base + sc[t] - cnt[t];
        nextOff[t] = off0;
        float di = rsqrtf((float)degfix[t] * (1.0f / FIXSCALE) + 1.0f);
        dl[t] = di;
        int gn = k * 128 + t;
        if (gn < N) { rowp[gn] = off0; dinv[gn] = di; }
    }
    __syncthreads();
    for (int i = base + t; i < endb; i += 256) {
        u64 r = tmp[i];
        int lid = (int)(r >> 23) & 127;
        int slot = atomicAdd(&nextOff[lid], 1);
        float ew = (float)(unsigned)(r & 0x7fffff) * (1.0f / FIXSCALE);
        float w = ew * dl[lid];                        // ew * dinv[dst]
        entries[slot] = make_int2((int)(r >> 30), __float_as_int(w));
    }
}

// W1[256,128] f32 -> Wt_hi[128,256] bf16 (transposed)
__global__ void k_wsplit(const float* __restrict__ W1, u16* __restrict__ wt_hi) {
    int idx = blockIdx.x * 256 + threadIdx.x;
    if (idx < 256 * 128) {
        int n = idx & 127, k = idx >> 7;
        wt_hi[n * 256 + k] = f2bf(W1[idx]);
    }
}

// gather layer 1: agg1[n] = dinv^2[n]*xw1[n] + sum_e (w_e*dinv[src_e])*xw1[src_e]
__launch_bounds__(256)
__global__ void k_gather1(const u16* __restrict__ xw1, const int2* __restrict__ entries,
                          const int* __restrict__ row, const float* __restrict__ dinv,
                          u16* __restrict__ agg1, int N) {
    int g = (blockIdx.x * 256 + threadIdx.x) >> 5;
    if (g >= N) return;
    int j = (threadIdx.x & 31) * 4;
    float di = dinv[g];
    float d2 = di * di;
    ushort4 sv = *(const ushort4*)(xw1 + (size_t)g * 128 + j);
    float4 acc = make_float4(d2 * bf2f(sv.x), d2 * bf2f(sv.y),
                             d2 * bf2f(sv.z), d2 * bf2f(sv.w));
    int e = row[g], end = row[g + 1];
    for (; e + 4 <= end; e += 4) {
        int2 e0 = entries[e];
        int2 e1 = entries[e + 1];
        int2 e2 = entries[e + 2];
        int2 e3 = entries[e + 3];
        ushort4 v0 = *(const ushort4*)(xw1 + (size_t)e0.x * 128 + j);
        ushort4 v1 = *(const ushort4*)(xw1 + (size_t)e1.x * 128 + j);
        ushort4 v2 = *(const ushort4*)(xw1 + (size_t)e2.x * 128 + j);
        ushort4 v3 = *(const ushort4*)(xw1 + (size_t)e3.x * 128 + j);
        float w0 = __int_as_float(e0.y) * dinv[e0.x];
        float w1 = __int_as_float(e1.y) * dinv[e1.x];
        float w2 = __int_as_float(e2.y) * dinv[e2.x];
        float w3 = __int_as_float(e3.y) * dinv[e3.x];
        acc.x += w0 * bf2f(v0.x) + w1 * bf2f(v1.x) + w2 * bf2f(v2.x) + w3 * bf2f(v3.x);
        acc.y += w0 * bf2f(v0.y) + w1 * bf2f(v1.y) + w2 * bf2f(v2.y) + w3 * bf2f(v3.y);
        acc.z += w0 * bf2f(v0.z) + w1 * bf2f(v1.z) + w2 * bf2f(v2.z) + w3 * bf2f(v3.z);
        acc.w += w0 * bf2f(v0.w) + w1 * bf2f(v1.w) + w2 * bf2f(v2.w) + w3 * bf2f(v3.w);
    }
    for (; e < end; ++e) {
        int2 e0 = entries[e];
        ushort4 v0 = *(const ushort4*)(xw1 + (size_t)e0.x * 128 + j);
        float w0 = __int_as_float(e0.y) * dinv[e0.x];
        acc.x += w0 * bf2f(v0.x);
        acc.y += w0 * bf2f(v0.y);
        acc.z += w0 * bf2f(v0.z);
        acc.w += w0 * bf2f(v0.w);
    }
    ushort4 o;
    o.x = f2bf(acc.x);
    o.y = f2bf(acc.y);
    o.z = f2bf(acc.z);
    o.w = f2bf(acc.w);
    *(ushort4*)(agg1 + (size_t)g * 128 + j) = o;
}

// GEMM2: h = relu(agg1 + b1); hw2[N,64](bf16) = dinv[row] * (h @ W2), pad 0
__launch_bounds__(320)
__global__ void k_gemm2(const u16* __restrict__ agg1, const float* __restrict__ W2,
                        const float* __restrict__ b1, const float* __restrict__ dinv,
                        u16* __restrict__ hw2, int N) {
    __shared__ float As[64 * 132];
    __shared__ float Bs[128 * 40];
    const int t = threadIdx.x;
    const int row0 = blockIdx.x * 64;

    for (int flat = t; flat < 128 * 40; flat += 320) Bs[flat] = W2[flat];

#pragma unroll
    for (int i = 0; i < 7; ++i) {
        int flat = t + i * 320;
        if (flat < 2048) {
            int r = flat >> 5, c4 = flat & 31;
            int gr = row0 + r;
            float4 v = make_float4(0.f, 0.f, 0.f, 0.f);
            if (gr < N) {
                ushort4 s = *(const ushort4*)(agg1 + (size_t)gr * 128 + c4 * 4);
                float4 bb = *(const float4*)(b1 + c4 * 4);
                v.x = fmaxf(bf2f(s.x) + bb.x, 0.f);
                v.y = fmaxf(bf2f(s.y) + bb.y, 0.f);
                v.z = fmaxf(bf2f(s.z) + bb.z, 0.f);
                v.w = fmaxf(bf2f(s.w) + bb.w, 0.f);
            }
            *(float4*)(As + r * 132 + c4 * 4) = v;
        }
    }
    __syncthreads();

    const int tx = t % 40;
    const int ty = t / 40;
    float acc[8];
#pragma unroll
    for (int r = 0; r < 8; ++r) acc[r] = 0.f;
    for (int k = 0; k < 128; ++k) {
        float b = Bs[k * 40 + tx];
#pragma unroll
        for (int r = 0; r < 8; ++r) acc[r] += As[(ty * 8 + r) * 132 + k] * b;
    }
#pragma unroll
    for (int r = 0; r < 8; ++r) {
        int gr = row0 + ty * 8 + r;
        if (gr < N) hw2[(size_t)gr * HW2S + tx] = f2bf(dinv[gr] * acc[r]);
    }
    for (int idx = t; idx < 64 * 24; idx += 320) {
        int r = idx / 24, c = 40 + idx % 24;
        int gr = row0 + r;
        if (gr < N) hw2[(size_t)gr * HW2S + c] = 0;
    }
}

// gather layer 2 + bias + fused L2 normalize -> out
__launch_bounds__(256)
__global__ void k_gather2(const u16* __restrict__ hw2, const int2* __restrict__ entries,
                          const int* __restrict__ row, const float* __restrict__ dinv,
                          const float* __restrict__ b2, float* __restrict__ out, int N) {
    int g = (blockIdx.x * 256 + threadIdx.x) >> 3;
    if (g >= N) return;
    int l = threadIdx.x & 7;
    int c0 = l * 8;
    float di = dinv[g];
    float bb[8];
#pragma unroll
    for (int k = 0; k < 8; ++k) bb[k] = (c0 + k < 40) ? b2[c0 + k] : 0.f;

    float acc[8];
    {
        short8 sv = *(const short8*)(hw2 + (size_t)g * HW2S + c0);
#pragma unroll
        for (int k = 0; k < 8; ++k) acc[k] = di * bf2f((u16)sv[k]) + bb[k];
    }
    int e = row[g], end = row[g + 1];
    for (; e + 2 <= end; e += 2) {
        int2 e0 = entries[e];
        int2 e1 = entries[e + 1];
        float w0 = __int_as_float(e0.y);      // ew*dinv[dst]; dinv[src] in hw2
        float w1 = __int_as_float(e1.y);
        short8 v0 = *(const short8*)(hw2 + (size_t)e0.x * HW2S + c0);
        short8 v1 = *(const short8*)(hw2 + (size_t)e1.x * HW2S + c0);
#pragma unroll
        for (int k = 0; k < 8; ++k)
            acc[k] += w0 * bf2f((u16)v0[k]) + w1 * bf2f((u16)v1[k]);
    }
    if (e < end) {
        int2 e0 = entries[e];
        float w0 = __int_as_float(e0.y);
        short8 v0 = *(const short8*)(hw2 + (size_t)e0.x * HW2S + c0);
#pragma unroll
        for (int k = 0; k < 8; ++k) acc[k] += w0 * bf2f((u16)v0[k]);
    }
    float ss = 0.f;
#pragma unroll
    for (int k = 0; k < 8; ++k) ss += acc[k] * acc[k];
    ss += __shfl_xor(ss, 1);
    ss += __shfl_xor(ss, 2);
    ss += __shfl_xor(ss, 4);
    float inv = 1.f / fmaxf(sqrtf(ss), 1e-12f);
    if (l < 5) {
        float* q = out + (size_t)g * 40 + c0;
        *(float4*)(q)     = make_float4(acc[0] * inv, acc[1] * inv, acc[2] * inv, acc[3] * inv);
        *(float4*)(q + 4) = make_float4(acc[4] * inv, acc[5] * inv, acc[6] * inv, acc[7] * inv);
    }
}

extern "C" void kernel_launch(void* const* d_in, const int* in_sizes, int n_in,
                              void* d_out, int out_size, void* d_ws, size_t ws_size,
                              hipStream_t stream) {
    const float* x   = (const float*)d_in[0];
    const int*   ei  = (const int*)d_in[1];
    const float* ew  = (const float*)d_in[2];
    const float* W1  = (const float*)d_in[3];
    const float* b1  = (const float*)d_in[4];
    const float* W2  = (const float*)d_in[5];
    const float* b2  = (const float*)d_in[6];
    float* out = (float*)d_out;

    const int N = in_sizes[0] / 256;   // 100000
    const int E = in_sizes[2];         // 1600000
    const int* src = ei;
    const int* dst = ei + E;
    const int NBUCK = (N + 127) >> 7;  // 782
    const int EPB = (E + NSLAB - 1) / NSLAB;

    char* ws = (char*)d_ws;
    size_t off = 0;
    auto take = [&](size_t bytes) -> void* {
        void* p = (void*)(ws + off);
        off += (bytes + 255) & ~(size_t)255;
        return p;
    };
    int*   cnt1    = (int*)take((size_t)NSLAB * NBUCK * 4);   // 2MB
    int*   colTot  = (int*)take((size_t)NBUCK * 4);
    int*   bucketBase = (int*)take((size_t)(NBUCK + 1) * 4);
    int*   rowp    = (int*)take((size_t)(N + 1) * 4);
    float* dinv    = (float*)take((size_t)N * 4);
    u64*   tmp     = (u64*)take((size_t)E * 8);               // 12.8MB (packed)
    int2*  entries = (int2*)take((size_t)E * 8);              // 12.8MB
    u16*   wt_hi   = (u16*)take((size_t)128 * 256 * 2);
    u16*   xw1     = (u16*)take((size_t)N * 128 * 2);
    u16*   agg1    = (u16*)take((size_t)N * 128 * 2);         // bf16
    u16*   hw2     = (u16*)take((size_t)N * HW2S * 2);        // 12.8MB

    k_wsplit<<<(256 * 128 + 255) / 256, 256, 0, stream>>>(W1, wt_hi);
    k_count<<<NSLAB, 256, 0, stream>>>(dst, cnt1, E, EPB, NBUCK);
    k_s2a<<<(NBUCK + SB - 1) / SB, 256, 0, stream>>>(cnt1, colTot, NBUCK);
    k_s2b<<<1, 1024, 0, stream>>>(colTot, bucketBase, rowp, NBUCK, N, E);

    const int gB = (N + 127) / 128;           // 782 gemm tiles
    k_fat<<<gB + NSLAB, 256, 0, stream>>>(x, wt_hi, xw1, N,
                                          src, dst, ew, cnt1, bucketBase, tmp,
                                          E, gB, EPB, NBUCK);

    k_s4<<<NBUCK, 256, 0, stream>>>(tmp, bucketBase, rowp, dinv, entries, N);

    k_gather1<<<(N * 32 + 255) / 256, 256, 0, stream>>>(xw1, entries, rowp, dinv, agg1, N);
    k_gemm2<<<(N + 63) / 64, 320, 0, stream>>>(agg1, W2, b1, dinv, hw2, N);
    k_gather2<<<(N * 8 + 255) / 256, 256, 0, stream>>>(hw2, entries, rowp, dinv, b2, out, N);
}

// Round 19
// 238.128 us; speedup vs baseline: 1.0221x; 1.0221x over previous
//
#include <hip/hip_runtime.h>

// ---------------------------------------------------------------------------
// 2-layer GCN forward (PyG GCNConv, add_self_loops, sym-norm), CSR-gather.
//   dinv = rsqrt(segsum(ew,dst)+1)
//   h    = relu( Agg(norm, x@W1) + dinv^2*(x@W1) + b1 )
//   out  = L2norm( Agg(norm, h@W2) + dinv^2*(h@W2) + b2 )
// CSR build = LDS counting sort (NO global atomics; 74us atomic cap R6-R9).
// Schedule: count -> s2a/s2b -> FAT(gemm1 || s3 scatter) -> s4.
// NSLAB=640 (384 unbalances the fat co-schedule: fat 80->89, R16).
// s2a = tiled coalesced I/O + chunked PARALLEL scan (R17's serial 640-iter
// column scan on 16 lanes was ~30us latency-bound; chunked depth ~85).
// GEMM1: single-pass bf16 W; register-prefetch pipeline + LDS-bounce epilogue.
// agg1 bf16. tmp packed 8B (src|lid|fix22). hw2 64-col bf16 pre-scaled.
// ---------------------------------------------------------------------------

typedef unsigned short u16;
typedef unsigned long long u64;
typedef __attribute__((ext_vector_type(8))) short short8;
typedef __attribute__((ext_vector_type(4))) float f32x4;

#define FIXSCALE 4194304.0f   // 2^22 fixed-point for deterministic deg
#define HW2S 64               // hw2 row stride (bf16), 40 real + 24 zero pad
#define NSLAB 640             // sort slabs (count/s3 blocks)
#define MAXBUCK 832           // LDS capacity for bucket counters (>= NBUCK)
#define SB 16                 // buckets per s2a block
#define CH 40                 // slabs per scan chunk (NSLAB = 16*CH)

static __device__ inline u16 f2bf(float f) {            // RNE f32 -> bf16 bits
    unsigned u = __float_as_uint(f);
    return (u16)((u + 0x7fffu + ((u >> 16) & 1u)) >> 16);
}
static __device__ inline float bf2f(u16 h) { return __uint_as_float(((unsigned)h) << 16); }

// pass 1: per-slab bucket histogram (LDS atomics only)
__launch_bounds__(256)
__global__ void k_count(const int* __restrict__ dst, int* __restrict__ cnt1,
                        int E, int EPB, int NBUCK) {
    __shared__ int cnt[MAXBUCK];
    int b = blockIdx.x;
    for (int j = threadIdx.x; j < NBUCK; j += 256) cnt[j] = 0;
    __syncthreads();
    int beg = b * EPB, end = min(beg + EPB, E);
    for (int i = beg + threadIdx.x; i < end; i += 256)
        atomicAdd(&cnt[dst[i] >> 7], 1);
    __syncthreads();
    for (int j = threadIdx.x; j < NBUCK; j += 256)
        cnt1[(size_t)b * NBUCK + j] = cnt[j];
}

// pass 2a: 16 buckets/block, coalesced strip I/O, chunked parallel scan.
// thread (jj = t&15 bucket, c = t>>4 chunk of 40 slabs)
__launch_bounds__(256)
__global__ void k_s2a(int* __restrict__ cnt1, int* __restrict__ colTot, int NBUCK) {
    __shared__ int d[NSLAB][SB + 1];
    __shared__ int csum[16][SB + 1];
    int j0 = blockIdx.x * SB;
    int nj = min(SB, NBUCK - j0);
    int t = threadIdx.x;
    for (int f = t; f < NSLAB * SB; f += 256) {
        int b = f >> 4, jj = f & 15;
        d[b][jj] = (jj < nj) ? cnt1[(size_t)b * NBUCK + j0 + jj] : 0;
    }
    __syncthreads();
    int jj = t & 15, c = t >> 4;
    // phase A: chunk sums (all 256 threads active)
    int s = 0;
#pragma unroll 8
    for (int b = c * CH; b < (c + 1) * CH; ++b) s += d[b][jj];
    csum[c][jj] = s;
    __syncthreads();
    // phase B: exclusive scan of the 16 chunk sums per bucket (16 lanes)
    if (c == 0) {
        int run = 0;
#pragma unroll
        for (int cc = 0; cc < 16; ++cc) {
            int v = csum[cc][jj];
            csum[cc][jj] = run;
            run += v;
        }
        if (jj < nj) colTot[j0 + jj] = run;
    }
    __syncthreads();
    // phase C: in-chunk exclusive prefix
    int run = csum[c][jj];
#pragma unroll 8
    for (int b = c * CH; b < (c + 1) * CH; ++b) {
        int v = d[b][jj];
        d[b][jj] = run;
        run += v;
    }
    __syncthreads();
    for (int f = t; f < NSLAB * SB; f += 256) {
        int b = f >> 4, jj2 = f & 15;
        if (jj2 < nj) cnt1[(size_t)b * NBUCK + j0 + jj2] = d[b][jj2];
    }
}

// pass 2b: scan bucket totals -> bucketBase; rowp[N]=E
__launch_bounds__(1024)
__global__ void k_s2b(const int* __restrict__ colTot, int* __restrict__ bucketBase,
                      int* __restrict__ rowp, int NBUCK, int N, int E) {
    __shared__ int s[1024];
    int t = threadIdx.x;
    int v = (t < NBUCK) ? colTot[t] : 0;
    s[t] = v;
    __syncthreads();
    for (int off = 1; off < 1024; off <<= 1) {
        int u = (t >= off) ? s[t - off] : 0;
        __syncthreads();
        s[t] += u;
        __syncthreads();
    }
    if (t < NBUCK) bucketBase[t] = s[t] - v;
    if (t == NBUCK - 1) bucketBase[NBUCK] = s[t];
    if (t == 0) rowp[N] = E;
}

// ---- FAT kernel: [0,gB) gemm1 tiles; [gB,gB+NSLAB) s3 scatter slabs -------
__launch_bounds__(256)
__global__ void k_fat(const float* __restrict__ x, const u16* __restrict__ wt_hi,
                      u16* __restrict__ xw1, int N,
                      const int* __restrict__ src, const int* __restrict__ dst,
                      const float* __restrict__ ew, const int* __restrict__ cnt1,
                      const int* __restrict__ bucketBase, u64* __restrict__ tmp,
                      int E, int gB, int EPB, int NBUCK) {
    __shared__ __align__(16) u16 S[10240];   // 20KB: Ah | Bh, reused by epilogue/s3
    u16* Ah = S;
    u16* Bh = S + 5120;

    if (blockIdx.x >= gB) {
        // ---- s3: scatter packed records to bucket-major tmp (LDS cursors) --
        int* ldsOff = (int*)S;
        int b = blockIdx.x - gB, t = threadIdx.x;
        for (int j = t; j < NBUCK; j += 256)
            ldsOff[j] = bucketBase[j] + cnt1[(size_t)b * NBUCK + j];
        __syncthreads();
        int beg = b * EPB, end = min(beg + EPB, E);
        for (int i = beg + t; i < end; i += 256) {
            int d = dst[i];
            int slot = atomicAdd(&ldsOff[d >> 7], 1);
            unsigned fix = (unsigned)__float2uint_rn(ew[i] * FIXSCALE);  // <= 2^22
            tmp[slot] = ((u64)(unsigned)src[i] << 30) | ((u64)(d & 127) << 23) | fix;
        }
        return;
    }

    // ------- gemm1: MFMA, LDS-staged, register-prefetch pipeline ----------
    const int t = threadIdx.x;
    const int w = t >> 6;
    const int lane = t & 63;
    const int lrow = lane & 15;
    const int q = lane >> 4;
    const int lk = q * 8;
    const int row0 = blockIdx.x * 128;

    int rA[4], cA[4];
    const float* pA[4];
    bool okA[4];
#pragma unroll
    for (int i = 0; i < 4; ++i) {
        int flat = t + i * 256;
        rA[i] = flat >> 3;
        cA[i] = flat & 7;
        int gr = row0 + rA[i];
        okA[i] = gr < N;
        pA[i] = x + (size_t)min(gr, N - 1) * 256 + cA[i] * 4;
    }
    int nB[2], cB[2];
    const u16* pB[2];
#pragma unroll
    for (int i = 0; i < 2; ++i) {
        int flat = t + i * 256;
        nB[i] = flat >> 2;
        cB[i] = flat & 3;
        pB[i] = wt_hi + (size_t)nB[i] * 256 + cB[i] * 8;
    }

    float4 ra[4];
    short8 rb[2];
#pragma unroll
    for (int i = 0; i < 4; ++i)
        ra[i] = okA[i] ? *(const float4*)(pA[i]) : make_float4(0.f, 0.f, 0.f, 0.f);
#pragma unroll
    for (int i = 0; i < 2; ++i) rb[i] = *(const short8*)(pB[i]);

    f32x4 acc[2][8] = {};

    for (int kt = 0; kt < 8; ++kt) {
#pragma unroll
        for (int i = 0; i < 4; ++i) {
            ushort4 vh;
            vh.x = f2bf(ra[i].x);
            vh.y = f2bf(ra[i].y);
            vh.z = f2bf(ra[i].z);
            vh.w = f2bf(ra[i].w);
            *(ushort4*)(Ah + rA[i] * 40 + cA[i] * 4) = vh;
        }
#pragma unroll
        for (int i = 0; i < 2; ++i)
            *(short8*)(Bh + nB[i] * 40 + cB[i] * 8) = rb[i];
        __syncthreads();

        if (kt < 7) {
#pragma unroll
            for (int i = 0; i < 4; ++i)
                ra[i] = okA[i] ? *(const float4*)(pA[i] + (kt + 1) * 32)
                               : make_float4(0.f, 0.f, 0.f, 0.f);
#pragma unroll
            for (int i = 0; i < 2; ++i)
                rb[i] = *(const short8*)(pB[i] + (kt + 1) * 32);
        }

        short8 a0 = *(const short8*)(Ah + (w * 32 + lrow) * 40 + lk);
        short8 a1 = *(const short8*)(Ah + (w * 32 + 16 + lrow) * 40 + lk);
#pragma unroll
        for (int ni = 0; ni < 8; ++ni) {
            short8 bh = *(const short8*)(Bh + (ni * 16 + lrow) * 40 + lk);
            acc[0][ni] = __builtin_amdgcn_mfma_f32_16x16x32_bf16(a0, bh, acc[0][ni], 0, 0, 0);
            acc[1][ni] = __builtin_amdgcn_mfma_f32_16x16x32_bf16(a1, bh, acc[1][ni], 0, 0, 0);
        }
        __syncthreads();
    }

    // ---- epilogue: LDS-bounce transpose -> coalesced 16B stores ----------
#pragma unroll
    for (int mi = 0; mi < 2; ++mi) {
        if (mi) __syncthreads();
#pragma unroll
        for (int r = 0; r < 4; ++r)
#pragma unroll
            for (int ni = 0; ni < 8; ++ni)
                S[(w * 16 + q * 4 + r) * 136 + lrow + ni * 16] = f2bf(acc[mi][ni][r]);
        __syncthreads();
        int l = t >> 2;
        int grow = row0 + (l >> 4) * 32 + mi * 16 + (l & 15);
        if (grow < N) {
#pragma unroll
            for (int c = 0; c < 4; ++c) {
                int col = (t & 3) * 8 + c * 32;
                *(short8*)(xw1 + (size_t)grow * 128 + col) =
                    *(const short8*)(S + l * 136 + col);
            }
        }
    }
}

// pass 4: per bucket (128 nodes): counts+deg (LDS), scan -> rowp/dinv,
// then write entries (src, ew*dinv_dst) to final contiguous slots.
__launch_bounds__(256)
__global__ void k_s4(const u64* __restrict__ tmp, const int* __restrict__ bucketBase,
                     int* __restrict__ rowp, float* __restrict__ dinv,
                     int2* __restrict__ entries, int N) {
    __shared__ int cnt[128];
    __shared__ unsigned degfix[128];
    __shared__ int sc[128];
    __shared__ int nextOff[128];
    __shared__ float dl[128];
    int k = blockIdx.x, t = threadIdx.x;
    int base = bucketBase[k], endb = bucketBase[k + 1];
    if (t < 128) { cnt[t] = 0; degfix[t] = 0; }
    __syncthreads();
    for (int i = base + t; i < endb; i += 256) {
        u64 r = tmp[i];
        int lid = (int)(r >> 23) & 127;
        atomicAdd(&cnt[lid], 1);
        atomicAdd(&degfix[lid], (unsigned)(r & 0x7fffff));
    }
    __syncthreads();
    if (t < 128) sc[t] = cnt[t];
    __syncthreads();
    for (int off = 1; off < 128; off <<= 1) {
        int u = 0;
        if (t < 128 && t >= off) u = sc[t - off];
        __syncthreads();
        if (t < 128) sc[t] += u;
        __syncthreads();
    }
    if (t < 128) {
        int off0 = base + sc[t] - cnt[t];
        nextOff[t] = off0;
        float di = rsqrtf((float)degfix[t] * (1.0f / FIXSCALE) + 1.0f);
        dl[t] = di;
        int gn = k * 128 + t;
        if (gn < N) { rowp[gn] = off0; dinv[gn] = di; }
    }
    __syncthreads();
    for (int i = base + t; i < endb; i += 256) {
        u64 r = tmp[i];
        int lid = (int)(r >> 23) & 127;
        int slot = atomicAdd(&nextOff[lid], 1);
        float ew = (float)(unsigned)(r & 0x7fffff) * (1.0f / FIXSCALE);
        float w = ew * dl[lid];                        // ew * dinv[dst]
        entries[slot] = make_int2((int)(r >> 30), __float_as_int(w));
    }
}

// W1[256,128] f32 -> Wt_hi[128,256] bf16 (transposed)
__global__ void k_wsplit(const float* __restrict__ W1, u16* __restrict__ wt_hi) {
    int idx = blockIdx.x * 256 + threadIdx.x;
    if (idx < 256 * 128) {
        int n = idx & 127, k = idx >> 7;
        wt_hi[n * 256 + k] = f2bf(W1[idx]);
    }
}

// gather layer 1: agg1[n] = dinv^2[n]*xw1[n] + sum_e (w_e*dinv[src_e])*xw1[src_e]
__launch_bounds__(256)
__global__ void k_gather1(const u16* __restrict__ xw1, const int2* __restrict__ entries,
                          const int* __restrict__ row, const float* __restrict__ dinv,
                          u16* __restrict__ agg1, int N) {
    int g = (blockIdx.x * 256 + threadIdx.x) >> 5;
    if (g >= N) return;
    int j = (threadIdx.x & 31) * 4;
    float di = dinv[g];
    float d2 = di * di;
    ushort4 sv = *(const ushort4*)(xw1 + (size_t)g * 128 + j);
    float4 acc = make_float4(d2 * bf2f(sv.x), d2 * bf2f(sv.y),
                             d2 * bf2f(sv.z), d2 * bf2f(sv.w));
    int e = row[g], end = row[g + 1];
    for (; e + 4 <= end; e += 4) {
        int2 e0 = entries[e];
        int2 e1 = entries[e + 1];
        int2 e2 = entries[e + 2];
        int2 e3 = entries[e + 3];
        ushort4 v0 = *(const ushort4*)(xw1 + (size_t)e0.x * 128 + j);
        ushort4 v1 = *(const ushort4*)(xw1 + (size_t)e1.x * 128 + j);
        ushort4 v2 = *(const ushort4*)(xw1 + (size_t)e2.x * 128 + j);
        ushort4 v3 = *(const ushort4*)(xw1 + (size_t)e3.x * 128 + j);
        float w0 = __int_as_float(e0.y) * dinv[e0.x];
        float w1 = __int_as_float(e1.y) * dinv[e1.x];
        float w2 = __int_as_float(e2.y) * dinv[e2.x];
        float w3 = __int_as_float(e3.y) * dinv[e3.x];
        acc.x += w0 * bf2f(v0.x) + w1 * bf2f(v1.x) + w2 * bf2f(v2.x) + w3 * bf2f(v3.x);
        acc.y += w0 * bf2f(v0.y) + w1 * bf2f(v1.y) + w2 * bf2f(v2.y) + w3 * bf2f(v3.y);
        acc.z += w0 * bf2f(v0.z) + w1 * bf2f(v1.z) + w2 * bf2f(v2.z) + w3 * bf2f(v3.z);
        acc.w += w0 * bf2f(v0.w) + w1 * bf2f(v1.w) + w2 * bf2f(v2.w) + w3 * bf2f(v3.w);
    }
    for (; e < end; ++e) {
        int2 e0 = entries[e];
        ushort4 v0 = *(const ushort4*)(xw1 + (size_t)e0.x * 128 + j);
        float w0 = __int_as_float(e0.y) * dinv[e0.x];
        acc.x += w0 * bf2f(v0.x);
        acc.y += w0 * bf2f(v0.y);
        acc.z += w0 * bf2f(v0.z);
        acc.w += w0 * bf2f(v0.w);
    }
    ushort4 o;
    o.x = f2bf(acc.x);
    o.y = f2bf(acc.y);
    o.z = f2bf(acc.z);
    o.w = f2bf(acc.w);
    *(ushort4*)(agg1 + (size_t)g * 128 + j) = o;
}

// GEMM2: h = relu(agg1 + b1); hw2[N,64](bf16) = dinv[row] * (h @ W2), pad 0
__launch_bounds__(320)
__global__ void k_gemm2(const u16* __restrict__ agg1, const float* __restrict__ W2,
                        const float* __restrict__ b1, const float* __restrict__ dinv,
                        u16* __restrict__ hw2, int N) {
    __shared__ float As[64 * 132];
    __shared__ float Bs[128 * 40];
    const int t = threadIdx.x;
    const int row0 = blockIdx.x * 64;

    for (int flat = t; flat < 128 * 40; flat += 320) Bs[flat] = W2[flat];

#pragma unroll
    for (int i = 0; i < 7; ++i) {
        int flat = t + i * 320;
        if (flat < 2048) {
            int r = flat >> 5, c4 = flat & 31;
            int gr = row0 + r;
            float4 v = make_float4(0.f, 0.f, 0.f, 0.f);
            if (gr < N) {
                ushort4 s = *(const ushort4*)(agg1 + (size_t)gr * 128 + c4 * 4);
                float4 bb = *(const float4*)(b1 + c4 * 4);
                v.x = fmaxf(bf2f(s.x) + bb.x, 0.f);
                v.y = fmaxf(bf2f(s.y) + bb.y, 0.f);
                v.z = fmaxf(bf2f(s.z) + bb.z, 0.f);
                v.w = fmaxf(bf2f(s.w) + bb.w, 0.f);
            }
            *(float4*)(As + r * 132 + c4 * 4) = v;
        }
    }
    __syncthreads();

    const int tx = t % 40;
    const int ty = t / 40;
    float acc[8];
#pragma unroll
    for (int r = 0; r < 8; ++r) acc[r] = 0.f;
    for (int k = 0; k < 128; ++k) {
        float b = Bs[k * 40 + tx];
#pragma unroll
        for (int r = 0; r < 8; ++r) acc[r] += As[(ty * 8 + r) * 132 + k] * b;
    }
#pragma unroll
    for (int r = 0; r < 8; ++r) {
        int gr = row0 + ty * 8 + r;
        if (gr < N) hw2[(size_t)gr * HW2S + tx] = f2bf(dinv[gr] * acc[r]);
    }
    for (int idx = t; idx < 64 * 24; idx += 320) {
        int r = idx / 24, c = 40 + idx % 24;
        int gr = row0 + r;
        if (gr < N) hw2[(size_t)gr * HW2S + c] = 0;
    }
}

// gather layer 2 + bias + fused L2 normalize -> out
__launch_bounds__(256)
__global__ void k_gather2(const u16* __restrict__ hw2, const int2* __restrict__ entries,
                          const int* __restrict__ row, const float* __restrict__ dinv,
                          const float* __restrict__ b2, float* __restrict__ out, int N) {
    int g = (blockIdx.x * 256 + threadIdx.x) >> 3;
    if (g >= N) return;
    int l = threadIdx.x & 7;
    int c0 = l * 8;
    float di = dinv[g];
    float bb[8];
#pragma unroll
    for (int k = 0; k < 8; ++k) bb[k] = (c0 + k < 40) ? b2[c0 + k] : 0.f;

    float acc[8];
    {
        short8 sv = *(const short8*)(hw2 + (size_t)g * HW2S + c0);
#pragma unroll
        for (int k = 0; k < 8; ++k) acc[k] = di * bf2f((u16)sv[k]) + bb[k];
    }
    int e = row[g], end = row[g + 1];
    for (; e + 2 <= end; e += 2) {
        int2 e0 = entries[e];
        int2 e1 = entries[e + 1];
        float w0 = __int_as_float(e0.y);      // ew*dinv[dst]; dinv[src] in hw2
        float w1 = __int_as_float(e1.y);
        short8 v0 = *(const short8*)(hw2 + (size_t)e0.x * HW2S + c0);
        short8 v1 = *(const short8*)(hw2 + (size_t)e1.x * HW2S + c0);
#pragma unroll
        for (int k = 0; k < 8; ++k)
            acc[k] += w0 * bf2f((u16)v0[k]) + w1 * bf2f((u16)v1[k]);
    }
    if (e < end) {
        int2 e0 = entries[e];
        float w0 = __int_as_float(e0.y);
        short8 v0 = *(const short8*)(hw2 + (size_t)e0.x * HW2S + c0);
#pragma unroll
        for (int k = 0; k < 8; ++k) acc[k] += w0 * bf2f((u16)v0[k]);
    }
    float ss = 0.f;
#pragma unroll
    for (int k = 0; k < 8; ++k) ss += acc[k] * acc[k];
    ss += __shfl_xor(ss, 1);
    ss += __shfl_xor(ss, 2);
    ss += __shfl_xor(ss, 4);
    float inv = 1.f / fmaxf(sqrtf(ss), 1e-12f);
    if (l < 5) {
        float* q = out + (size_t)g * 40 + c0;
        *(float4*)(q)     = make_float4(acc[0] * inv, acc[1] * inv, acc[2] * inv, acc[3] * inv);
        *(float4*)(q + 4) = make_float4(acc[4] * inv, acc[5] * inv, acc[6] * inv, acc[7] * inv);
    }
}

extern "C" void kernel_launch(void* const* d_in, const int* in_sizes, int n_in,
                              void* d_out, int out_size, void* d_ws, size_t ws_size,
                              hipStream_t stream) {
    const float* x   = (const float*)d_in[0];
    const int*   ei  = (const int*)d_in[1];
    const float* ew  = (const float*)d_in[2];
    const float* W1  = (const float*)d_in[3];
    const float* b1  = (const float*)d_in[4];
    const float* W2  = (const float*)d_in[5];
    const float* b2  = (const float*)d_in[6];
    float* out = (float*)d_out;

    const int N = in_sizes[0] / 256;   // 100000
    const int E = in_sizes[2];         // 1600000
    const int* src = ei;
    const int* dst = ei + E;
    const int NBUCK = (N + 127) >> 7;  // 782
    const int EPB = (E + NSLAB - 1) / NSLAB;

    char* ws = (char*)d_ws;
    size_t off = 0;
    auto take = [&](size_t bytes) -> void* {
        void* p = (void*)(ws + off);
        off += (bytes + 255) & ~(size_t)255;
        return p;
    };
    int*   cnt1    = (int*)take((size_t)NSLAB * NBUCK * 4);   // 2MB
    int*   colTot  = (int*)take((size_t)NBUCK * 4);
    int*   bucketBase = (int*)take((size_t)(NBUCK + 1) * 4);
    int*   rowp    = (int*)take((size_t)(N + 1) * 4);
    float* dinv    = (float*)take((size_t)N * 4);
    u64*   tmp     = (u64*)take((size_t)E * 8);               // 12.8MB (packed)
    int2*  entries = (int2*)take((size_t)E * 8);              // 12.8MB
    u16*   wt_hi   = (u16*)take((size_t)128 * 256 * 2);
    u16*   xw1     = (u16*)take((size_t)N * 128 * 2);
    u16*   agg1    = (u16*)take((size_t)N * 128 * 2);         // bf16
    u16*   hw2     = (u16*)take((size_t)N * HW2S * 2);        // 12.8MB

    k_wsplit<<<(256 * 128 + 255) / 256, 256, 0, stream>>>(W1, wt_hi);
    k_count<<<NSLAB, 256, 0, stream>>>(dst, cnt1, E, EPB, NBUCK);
    k_s2a<<<(NBUCK + SB - 1) / SB, 256, 0, stream>>>(cnt1, colTot, NBUCK);
    k_s2b<<<1, 1024, 0, stream>>>(colTot, bucketBase, rowp, NBUCK, N, E);

    const int gB = (N + 127) / 128;           // 782 gemm tiles
    k_fat<<<gB + NSLAB, 256, 0, stream>>>(x, wt_hi, xw1, N,
                                          src, dst, ew, cnt1, bucketBase, tmp,
                                          E, gB, EPB, NBUCK);

    k_s4<<<NBUCK, 256, 0, stream>>>(tmp, bucketBase, rowp, dinv, entries, N);

    k_gather1<<<(N * 32 + 255) / 256, 256, 0, stream>>>(xw1, entries, rowp, dinv, agg1, N);
    k_gemm2<<<(N + 63) / 64, 320, 0, stream>>>(agg1, W2, b1, dinv, hw2, N);
    k_gather2<<<(N * 8 + 255) / 256, 256, 0, stream>>>(hw2, entries, rowp, dinv, b2, out, N);
}

// Round 20
// 237.868 us; speedup vs baseline: 1.0233x; 1.0011x over previous
//
#include <hip/hip_runtime.h>

// ---------------------------------------------------------------------------
// 2-layer GCN forward (PyG GCNConv, add_self_loops, sym-norm), CSR-gather.
//   dinv = rsqrt(segsum(ew,dst)+1)
//   h    = relu( Agg(norm, x@W1) + dinv^2*(x@W1) + b1 )
//   out  = L2norm( Agg(norm, h@W2) + dinv^2*(h@W2) + b2 )
// CSR build = LDS counting sort (NO global atomics; 74us atomic cap R6-R9).
// Schedule: count -> s2a/s2b -> FAT(gemm1 || s3 scatter) -> s4.
// GEMM1: single-pass bf16 W; register-prefetch + DOUBLE-BUFFERED LDS
// (1 barrier per K-step instead of 2; R15 proved barrier-drain is the binder).
// agg1 bf16. tmp packed 8B (src|lid|fix22). hw2 64-col bf16 pre-scaled.
// ---------------------------------------------------------------------------

typedef unsigned short u16;
typedef unsigned long long u64;
typedef __attribute__((ext_vector_type(8))) short short8;
typedef __attribute__((ext_vector_type(4))) float f32x4;

#define FIXSCALE 4194304.0f   // 2^22 fixed-point for deterministic deg
#define HW2S 64               // hw2 row stride (bf16), 40 real + 24 zero pad
#define NSLAB 640             // sort slabs (count/s3 blocks)
#define MAXBUCK 832           // LDS capacity for bucket counters (>= NBUCK)
#define SB 16                 // buckets per s2a block
#define CH 40                 // slabs per scan chunk (NSLAB = 16*CH)

static __device__ inline u16 f2bf(float f) {            // RNE f32 -> bf16 bits
    unsigned u = __float_as_uint(f);
    return (u16)((u + 0x7fffu + ((u >> 16) & 1u)) >> 16);
}
static __device__ inline float bf2f(u16 h) { return __uint_as_float(((unsigned)h) << 16); }

// pass 1: per-slab bucket histogram (LDS atomics only)
__launch_bounds__(256)
__global__ void k_count(const int* __restrict__ dst, int* __restrict__ cnt1,
                        int E, int EPB, int NBUCK) {
    __shared__ int cnt[MAXBUCK];
    int b = blockIdx.x;
    for (int j = threadIdx.x; j < NBUCK; j += 256) cnt[j] = 0;
    __syncthreads();
    int beg = b * EPB, end = min(beg + EPB, E);
    for (int i = beg + threadIdx.x; i < end; i += 256)
        atomicAdd(&cnt[dst[i] >> 7], 1);
    __syncthreads();
    for (int j = threadIdx.x; j < NBUCK; j += 256)
        cnt1[(size_t)b * NBUCK + j] = cnt[j];
}

// pass 2a: 16 buckets/block, coalesced strip I/O, chunked parallel scan.
__launch_bounds__(256)
__global__ void k_s2a(int* __restrict__ cnt1, int* __restrict__ colTot, int NBUCK) {
    __shared__ int d[NSLAB][SB + 1];
    __shared__ int csum[16][SB + 1];
    int j0 = blockIdx.x * SB;
    int nj = min(SB, NBUCK - j0);
    int t = threadIdx.x;
    for (int f = t; f < NSLAB * SB; f += 256) {
        int b = f >> 4, jj = f & 15;
        d[b][jj] = (jj < nj) ? cnt1[(size_t)b * NBUCK + j0 + jj] : 0;
    }
    __syncthreads();
    int jj = t & 15, c = t >> 4;
    int s = 0;
#pragma unroll 8
    for (int b = c * CH; b < (c + 1) * CH; ++b) s += d[b][jj];
    csum[c][jj] = s;
    __syncthreads();
    if (c == 0) {
        int run = 0;
#pragma unroll
        for (int cc = 0; cc < 16; ++cc) {
            int v = csum[cc][jj];
            csum[cc][jj] = run;
            run += v;
        }
        if (jj < nj) colTot[j0 + jj] = run;
    }
    __syncthreads();
    int run = csum[c][jj];
#pragma unroll 8
    for (int b = c * CH; b < (c + 1) * CH; ++b) {
        int v = d[b][jj];
        d[b][jj] = run;
        run += v;
    }
    __syncthreads();
    for (int f = t; f < NSLAB * SB; f += 256) {
        int b = f >> 4, jj2 = f & 15;
        if (jj2 < nj) cnt1[(size_t)b * NBUCK + j0 + jj2] = d[b][jj2];
    }
}

// pass 2b: scan bucket totals -> bucketBase; rowp[N]=E
__launch_bounds__(1024)
__global__ void k_s2b(const int* __restrict__ colTot, int* __restrict__ bucketBase,
                      int* __restrict__ rowp, int NBUCK, int N, int E) {
    __shared__ int s[1024];
    int t = threadIdx.x;
    int v = (t < NBUCK) ? colTot[t] : 0;
    s[t] = v;
    __syncthreads();
    for (int off = 1; off < 1024; off <<= 1) {
        int u = (t >= off) ? s[t - off] : 0;
        __syncthreads();
        s[t] += u;
        __syncthreads();
    }
    if (t < NBUCK) bucketBase[t] = s[t] - v;
    if (t == NBUCK - 1) bucketBase[NBUCK] = s[t];
    if (t == 0) rowp[N] = E;
}

// ---- FAT kernel: [0,gB) gemm1 tiles; [gB,gB+NSLAB) s3 scatter slabs -------
__launch_bounds__(256)
__global__ void k_fat(const float* __restrict__ x, const u16* __restrict__ wt_hi,
                      u16* __restrict__ xw1, int N,
                      const int* __restrict__ src, const int* __restrict__ dst,
                      const float* __restrict__ ew, const int* __restrict__ cnt1,
                      const int* __restrict__ bucketBase, u64* __restrict__ tmp,
                      int E, int gB, int EPB, int NBUCK) {
    __shared__ __align__(16) u16 S[20480];   // 40KB: double-buffered Ah|Bh
    u16* A0 = S;
    u16* B0 = S + 5120;
    u16* A1 = S + 10240;
    u16* B1 = S + 15360;

    if (blockIdx.x >= gB) {
        // ---- s3: scatter packed records to bucket-major tmp (LDS cursors) --
        int* ldsOff = (int*)S;
        int b = blockIdx.x - gB, t = threadIdx.x;
        for (int j = t; j < NBUCK; j += 256)
            ldsOff[j] = bucketBase[j] + cnt1[(size_t)b * NBUCK + j];
        __syncthreads();
        int beg = b * EPB, end = min(beg + EPB, E);
        for (int i = beg + t; i < end; i += 256) {
            int d = dst[i];
            int slot = atomicAdd(&ldsOff[d >> 7], 1);
            unsigned fix = (unsigned)__float2uint_rn(ew[i] * FIXSCALE);  // <= 2^22
            tmp[slot] = ((u64)(unsigned)src[i] << 30) | ((u64)(d & 127) << 23) | fix;
        }
        return;
    }

    // -- gemm1: MFMA, double-buffered LDS, reg-prefetch, 1 barrier/K-step --
    const int t = threadIdx.x;
    const int w = t >> 6;
    const int lane = t & 63;
    const int lrow = lane & 15;
    const int q = lane >> 4;
    const int lk = q * 8;
    const int row0 = blockIdx.x * 128;

    int rA[4], cA[4];
    const float* pA[4];
    bool okA[4];
#pragma unroll
    for (int i = 0; i < 4; ++i) {
        int flat = t + i * 256;
        rA[i] = flat >> 3;
        cA[i] = flat & 7;
        int gr = row0 + rA[i];
        okA[i] = gr < N;
        pA[i] = x + (size_t)min(gr, N - 1) * 256 + cA[i] * 4;
    }
    int nB[2], cB[2];
    const u16* pB[2];
#pragma unroll
    for (int i = 0; i < 2; ++i) {
        int flat = t + i * 256;
        nB[i] = flat >> 2;
        cB[i] = flat & 3;
        pB[i] = wt_hi + (size_t)nB[i] * 256 + cB[i] * 8;
    }

    float4 ra[4];
    short8 rb[2];
    // prologue: stage kt=0 into buf0, prefetch kt=1 into regs
#pragma unroll
    for (int i = 0; i < 4; ++i)
        ra[i] = okA[i] ? *(const float4*)(pA[i]) : make_float4(0.f, 0.f, 0.f, 0.f);
#pragma unroll
    for (int i = 0; i < 2; ++i) rb[i] = *(const short8*)(pB[i]);
#pragma unroll
    for (int i = 0; i < 4; ++i) {
        ushort4 vh;
        vh.x = f2bf(ra[i].x);
        vh.y = f2bf(ra[i].y);
        vh.z = f2bf(ra[i].z);
        vh.w = f2bf(ra[i].w);
        *(ushort4*)(A0 + rA[i] * 40 + cA[i] * 4) = vh;
    }
#pragma unroll
    for (int i = 0; i < 2; ++i)
        *(short8*)(B0 + nB[i] * 40 + cB[i] * 8) = rb[i];
#pragma unroll
    for (int i = 0; i < 4; ++i)
        ra[i] = okA[i] ? *(const float4*)(pA[i] + 32) : make_float4(0.f, 0.f, 0.f, 0.f);
#pragma unroll
    for (int i = 0; i < 2; ++i) rb[i] = *(const short8*)(pB[i] + 32);
    __syncthreads();

    f32x4 acc[2][8] = {};

#pragma unroll
    for (int kt = 0; kt < 8; ++kt) {
        u16* Ac = (kt & 1) ? A1 : A0;
        u16* Bc = (kt & 1) ? B1 : B0;
        u16* An = (kt & 1) ? A0 : A1;
        u16* Bn = (kt & 1) ? B0 : B1;

        if (kt < 7) {
            // write kt+1 (in regs) to the other buffer
#pragma unroll
            for (int i = 0; i < 4; ++i) {
                ushort4 vh;
                vh.x = f2bf(ra[i].x);
                vh.y = f2bf(ra[i].y);
                vh.z = f2bf(ra[i].z);
                vh.w = f2bf(ra[i].w);
                *(ushort4*)(An + rA[i] * 40 + cA[i] * 4) = vh;
            }
#pragma unroll
            for (int i = 0; i < 2; ++i)
                *(short8*)(Bn + nB[i] * 40 + cB[i] * 8) = rb[i];
        }
        if (kt < 6) {
            // issue kt+2 loads; latency hides under this step's MFMA
#pragma unroll
            for (int i = 0; i < 4; ++i)
                ra[i] = okA[i] ? *(const float4*)(pA[i] + (kt + 2) * 32)
                               : make_float4(0.f, 0.f, 0.f, 0.f);
#pragma unroll
            for (int i = 0; i < 2; ++i)
                rb[i] = *(const short8*)(pB[i] + (kt + 2) * 32);
        }

        short8 a0 = *(const short8*)(Ac + (w * 32 + lrow) * 40 + lk);
        short8 a1 = *(const short8*)(Ac + (w * 32 + 16 + lrow) * 40 + lk);
#pragma unroll
        for (int ni = 0; ni < 8; ++ni) {
            short8 bh = *(const short8*)(Bc + (ni * 16 + lrow) * 40 + lk);
            acc[0][ni] = __builtin_amdgcn_mfma_f32_16x16x32_bf16(a0, bh, acc[0][ni], 0, 0, 0);
            acc[1][ni] = __builtin_amdgcn_mfma_f32_16x16x32_bf16(a1, bh, acc[1][ni], 0, 0, 0);
        }
        __syncthreads();
    }

    // ---- epilogue: LDS-bounce transpose -> coalesced 16B stores ----------
#pragma unroll
    for (int mi = 0; mi < 2; ++mi) {
        if (mi) __syncthreads();   // mi=0 covered by loop's last barrier
#pragma unroll
        for (int r = 0; r < 4; ++r)
#pragma unroll
            for (int ni = 0; ni < 8; ++ni)
                S[(w * 16 + q * 4 + r) * 136 + lrow + ni * 16] = f2bf(acc[mi][ni][r]);
        __syncthreads();
        int l = t >> 2;
        int grow = row0 + (l >> 4) * 32 + mi * 16 + (l & 15);
        if (grow < N) {
#pragma unroll
            for (int c = 0; c < 4; ++c) {
                int col = (t & 3) * 8 + c * 32;
                *(short8*)(xw1 + (size_t)grow * 128 + col) =
                    *(const short8*)(S + l * 136 + col);
            }
        }
    }
}

// pass 4: per bucket (128 nodes): counts+deg (LDS), scan -> rowp/dinv,
// then write entries (src, ew*dinv_dst) to final contiguous slots.
__launch_bounds__(256)
__global__ void k_s4(const u64* __restrict__ tmp, const int* __restrict__ bucketBase,
                     int* __restrict__ rowp, float* __restrict__ dinv,
                     int2* __restrict__ entries, int N) {
    __shared__ int cnt[128];
    __shared__ unsigned degfix[128];
    __shared__ int sc[128];
    __shared__ int nextOff[128];
    __shared__ float dl[128];
    int k = blockIdx.x, t = threadIdx.x;
    int base = bucketBase[k], endb = bucketBase[k + 1];
    if (t < 128) { cnt[t] = 0; degfix[t] = 0; }
    __syncthreads();
    for (int i = base + t; i < endb; i += 256) {
        u64 r = tmp[i];
        int lid = (int)(r >> 23) & 127;
        atomicAdd(&cnt[lid], 1);
        atomicAdd(&degfix[lid], (unsigned)(r & 0x7fffff));
    }
    __syncthreads();
    if (t < 128) sc[t] = cnt[t];
    __syncthreads();
    for (int off = 1; off < 128; off <<= 1) {
        int u = 0;
        if (t < 128 && t >= off) u = sc[t - off];
        __syncthreads();
        if (t < 128) sc[t] += u;
        __syncthreads();
    }
    if (t < 128) {
        int off0 = base + sc[t] - cnt[t];
        nextOff[t] = off0;
        float di = rsqrtf((float)degfix[t] * (1.0f / FIXSCALE) + 1.0f);
        dl[t] = di;
        int gn = k * 128 + t;
        if (gn < N) { rowp[gn] = off0; dinv[gn] = di; }
    }
    __syncthreads();
    for (int i = base + t; i < endb; i += 256) {
        u64 r = tmp[i];
        int lid = (int)(r >> 23) & 127;
        int slot = atomicAdd(&nextOff[lid], 1);
        float ew = (float)(unsigned)(r & 0x7fffff) * (1.0f / FIXSCALE);
        float w = ew * dl[lid];                        // ew * dinv[dst]
        entries[slot] = make_int2((int)(r >> 30), __float_as_int(w));
    }
}

// W1[256,128] f32 -> Wt_hi[128,256] bf16 (transposed)
__global__ void k_wsplit(const float* __restrict__ W1, u16* __restrict__ wt_hi) {
    int idx = blockIdx.x * 256 + threadIdx.x;
    if (idx < 256 * 128) {
        int n = idx & 127, k = idx >> 7;
        wt_hi[n * 256 + k] = f2bf(W1[idx]);
    }
}

// gather layer 1: agg1[n] = dinv^2[n]*xw1[n] + sum_e (w_e*dinv[src_e])*xw1[src_e]
__launch_bounds__(256)
__global__ void k_gather1(const u16* __restrict__ xw1, const int2* __restrict__ entries,
                          const int* __restrict__ row, const float* __restrict__ dinv,
                          u16* __restrict__ agg1, int N) {
    int g = (blockIdx.x * 256 + threadIdx.x) >> 5;
    if (g >= N) return;
    int j = (threadIdx.x & 31) * 4;
    float di = dinv[g];
    float d2 = di * di;
    ushort4 sv = *(const ushort4*)(xw1 + (size_t)g * 128 + j);
    float4 acc = make_float4(d2 * bf2f(sv.x), d2 * bf2f(sv.y),
                             d2 * bf2f(sv.z), d2 * bf2f(sv.w));
    int e = row[g], end = row[g + 1];
    for (; e + 4 <= end; e += 4) {
        int2 e0 = entries[e];
        int2 e1 = entries[e + 1];
        int2 e2 = entries[e + 2];
        int2 e3 = entries[e + 3];
        ushort4 v0 = *(const ushort4*)(xw1 + (size_t)e0.x * 128 + j);
        ushort4 v1 = *(const ushort4*)(xw1 + (size_t)e1.x * 128 + j);
        ushort4 v2 = *(const ushort4*)(xw1 + (size_t)e2.x * 128 + j);
        ushort4 v3 = *(const ushort4*)(xw1 + (size_t)e3.x * 128 + j);
        float w0 = __int_as_float(e0.y) * dinv[e0.x];
        float w1 = __int_as_float(e1.y) * dinv[e1.x];
        float w2 = __int_as_float(e2.y) * dinv[e2.x];
        float w3 = __int_as_float(e3.y) * dinv[e3.x];
        acc.x += w0 * bf2f(v0.x) + w1 * bf2f(v1.x) + w2 * bf2f(v2.x) + w3 * bf2f(v3.x);
        acc.y += w0 * bf2f(v0.y) + w1 * bf2f(v1.y) + w2 * bf2f(v2.y) + w3 * bf2f(v3.y);
        acc.z += w0 * bf2f(v0.z) + w1 * bf2f(v1.z) + w2 * bf2f(v2.z) + w3 * bf2f(v3.z);
        acc.w += w0 * bf2f(v0.w) + w1 * bf2f(v1.w) + w2 * bf2f(v2.w) + w3 * bf2f(v3.w);
    }
    for (; e < end; ++e) {
        int2 e0 = entries[e];
        ushort4 v0 = *(const ushort4*)(xw1 + (size_t)e0.x * 128 + j);
        float w0 = __int_as_float(e0.y) * dinv[e0.x];
        acc.x += w0 * bf2f(v0.x);
        acc.y += w0 * bf2f(v0.y);
        acc.z += w0 * bf2f(v0.z);
        acc.w += w0 * bf2f(v0.w);
    }
    ushort4 o;
    o.x = f2bf(acc.x);
    o.y = f2bf(acc.y);
    o.z = f2bf(acc.z);
    o.w = f2bf(acc.w);
    *(ushort4*)(agg1 + (size_t)g * 128 + j) = o;
}

// GEMM2: h = relu(agg1 + b1); hw2[N,64](bf16) = dinv[row] * (h @ W2), pad 0
__launch_bounds__(320)
__global__ void k_gemm2(const u16* __restrict__ agg1, const float* __restrict__ W2,
                        const float* __restrict__ b1, const float* __restrict__ dinv,
                        u16* __restrict__ hw2, int N) {
    __shared__ float As[64 * 132];
    __shared__ float Bs[128 * 40];
    const int t = threadIdx.x;
    const int row0 = blockIdx.x * 64;

    for (int flat = t; flat < 128 * 40; flat += 320) Bs[flat] = W2[flat];

#pragma unroll
    for (int i = 0; i < 7; ++i) {
        int flat = t + i * 320;
        if (flat < 2048) {
            int r = flat >> 5, c4 = flat & 31;
            int gr = row0 + r;
            float4 v = make_float4(0.f, 0.f, 0.f, 0.f);
            if (gr < N) {
                ushort4 s = *(const ushort4*)(agg1 + (size_t)gr * 128 + c4 * 4);
                float4 bb = *(const float4*)(b1 + c4 * 4);
                v.x = fmaxf(bf2f(s.x) + bb.x, 0.f);
                v.y = fmaxf(bf2f(s.y) + bb.y, 0.f);
                v.z = fmaxf(bf2f(s.z) + bb.z, 0.f);
                v.w = fmaxf(bf2f(s.w) + bb.w, 0.f);
            }
            *(float4*)(As + r * 132 + c4 * 4) = v;
        }
    }
    __syncthreads();

    const int tx = t % 40;
    const int ty = t / 40;
    float acc[8];
#pragma unroll
    for (int r = 0; r < 8; ++r) acc[r] = 0.f;
    for (int k = 0; k < 128; ++k) {
        float b = Bs[k * 40 + tx];
#pragma unroll
        for (int r = 0; r < 8; ++r) acc[r] += As[(ty * 8 + r) * 132 + k] * b;
    }
#pragma unroll
    for (int r = 0; r < 8; ++r) {
        int gr = row0 + ty * 8 + r;
        if (gr < N) hw2[(size_t)gr * HW2S + tx] = f2bf(dinv[gr] * acc[r]);
    }
    for (int idx = t; idx < 64 * 24; idx += 320) {
        int r = idx / 24, c = 40 + idx % 24;
        int gr = row0 + r;
        if (gr < N) hw2[(size_t)gr * HW2S + c] = 0;
    }
}

// gather layer 2 + bias + fused L2 normalize -> out
__launch_bounds__(256)
__global__ void k_gather2(const u16* __restrict__ hw2, const int2* __restrict__ entries,
                          const int* __restrict__ row, const float* __restrict__ dinv,
                          const float* __restrict__ b2, float* __restrict__ out, int N) {
    int g = (blockIdx.x * 256 + threadIdx.x) >> 3;
    if (g >= N) return;
    int l = threadIdx.x & 7;
    int c0 = l * 8;
    float di = dinv[g];
    float bb[8];
#pragma unroll
    for (int k = 0; k < 8; ++k) bb[k] = (c0 + k < 40) ? b2[c0 + k] : 0.f;

    float acc[8];
    {
        short8 sv = *(const short8*)(hw2 + (size_t)g * HW2S + c0);
#pragma unroll
        for (int k = 0; k < 8; ++k) acc[k] = di * bf2f((u16)sv[k]) + bb[k];
    }
    int e = row[g], end = row[g + 1];
    for (; e + 2 <= end; e += 2) {
        int2 e0 = entries[e];
        int2 e1 = entries[e + 1];
        float w0 = __int_as_float(e0.y);      // ew*dinv[dst]; dinv[src] in hw2
        float w1 = __int_as_float(e1.y);
        short8 v0 = *(const short8*)(hw2 + (size_t)e0.x * HW2S + c0);
        short8 v1 = *(const short8*)(hw2 + (size_t)e1.x * HW2S + c0);
#pragma unroll
        for (int k = 0; k < 8; ++k)
            acc[k] += w0 * bf2f((u16)v0[k]) + w1 * bf2f((u16)v1[k]);
    }
    if (e < end) {
        int2 e0 = entries[e];
        float w0 = __int_as_float(e0.y);
        short8 v0 = *(const short8*)(hw2 + (size_t)e0.x * HW2S + c0);
#pragma unroll
        for (int k = 0; k < 8; ++k) acc[k] += w0 * bf2f((u16)v0[k]);
    }
    float ss = 0.f;
#pragma unroll
    for (int k = 0; k < 8; ++k) ss += acc[k] * acc[k];
    ss += __shfl_xor(ss, 1);
    ss += __shfl_xor(ss, 2);
    ss += __shfl_xor(ss, 4);
    float inv = 1.f / fmaxf(sqrtf(ss), 1e-12f);
    if (l < 5) {
        float* q = out + (size_t)g * 40 + c0;
        *(float4*)(q)     = make_float4(acc[0] * inv, acc[1] * inv, acc[2] * inv, acc[3] * inv);
        *(float4*)(q + 4) = make_float4(acc[4] * inv, acc[5] * inv, acc[6] * inv, acc[7] * inv);
    }
}

extern "C" void kernel_launch(void* const* d_in, const int* in_sizes, int n_in,
                              void* d_out, int out_size, void* d_ws, size_t ws_size,
                              hipStream_t stream) {
    const float* x   = (const float*)d_in[0];
    const int*   ei  = (const int*)d_in[1];
    const float* ew  = (const float*)d_in[2];
    const float* W1  = (const float*)d_in[3];
    const float* b1  = (const float*)d_in[4];
    const float* W2  = (const float*)d_in[5];
    const float* b2  = (const float*)d_in[6];
    float* out = (float*)d_out;

    const int N = in_sizes[0] / 256;   // 100000
    const int E = in_sizes[2];         // 1600000
    const int* src = ei;
    const int* dst = ei + E;
    const int NBUCK = (N + 127) >> 7;  // 782
    const int EPB = (E + NSLAB - 1) / NSLAB;

    char* ws = (char*)d_ws;
    size_t off = 0;
    auto take = [&](size_t bytes) -> void* {
        void* p = (void*)(ws + off);
        off += (bytes + 255) & ~(size_t)255;
        return p;
    };
    int*   cnt1    = (int*)take((size_t)NSLAB * NBUCK * 4);   // 2MB
    int*   colTot  = (int*)take((size_t)NBUCK * 4);
    int*   bucketBase = (int*)take((size_t)(NBUCK + 1) * 4);
    int*   rowp    = (int*)take((size_t)(N + 1) * 4);
    float* dinv    = (float*)take((size_t)N * 4);
    u64*   tmp     = (u64*)take((size_t)E * 8);               // 12.8MB (packed)
    int2*  entries = (int2*)take((size_t)E * 8);              // 12.8MB
    u16*   wt_hi   = (u16*)take((size_t)128 * 256 * 2);
    u16*   xw1     = (u16*)take((size_t)N * 128 * 2);
    u16*   agg1    = (u16*)take((size_t)N * 128 * 2);         // bf16
    u16*   hw2     = (u16*)take((size_t)N * HW2S * 2);        // 12.8MB

    k_wsplit<<<(256 * 128 + 255) / 256, 256, 0, stream>>>(W1, wt_hi);
    k_count<<<NSLAB, 256, 0, stream>>>(dst, cnt1, E, EPB, NBUCK);
    k_s2a<<<(NBUCK + SB - 1) / SB, 256, 0, stream>>>(cnt1, colTot, NBUCK);
    k_s2b<<<1, 1024, 0, stream>>>(colTot, bucketBase, rowp, NBUCK, N, E);

    const int gB = (N + 127) / 128;           // 782 gemm tiles
    k_fat<<<gB + NSLAB, 256, 0, stream>>>(x, wt_hi, xw1, N,
                                          src, dst, ew, cnt1, bucketBase, tmp,
                                          E, gB, EPB, NBUCK);

    k_s4<<<NBUCK, 256, 0, stream>>>(tmp, bucketBase, rowp, dinv, entries, N);

    k_gather1<<<(N * 32 + 255) / 256, 256, 0, stream>>>(xw1, entries, rowp, dinv, agg1, N);
    k_gemm2<<<(N + 63) / 64, 320, 0, stream>>>(agg1, W2, b1, dinv, hw2, N);
    k_gather2<<<(N * 8 + 255) / 256, 256, 0, stream>>>(hw2, entries, rowp, dinv, b2, out, N);
}

// Round 21
// 232.810 us; speedup vs baseline: 1.0455x; 1.0217x over previous
//
#include <hip/hip_runtime.h>

// ---------------------------------------------------------------------------
// 2-layer GCN forward (PyG GCNConv, add_self_loops, sym-norm), CSR-gather.
//   dinv = rsqrt(segsum(ew,dst)+1)
//   h    = relu( Agg(norm, x@W1) + dinv^2*(x@W1) + b1 )
//   out  = L2norm( Agg(norm, h@W2) + dinv^2*(h@W2) + b2 )
// CSR build = LDS counting sort (NO global atomics; 74us atomic cap R6-R9).
// Best-of-each reassembly (R20): NSLAB=640; ORIGINAL strided Hillis-Steele
// s2a (782 blocks — TLP hides the stride; R17/R18 "fixes" were slower);
// R15 single-buffered 20KB fat (dbuf R19 lost the gain to occupancy);
// agg1 bf16; gather1 16 lanes/node x 16B loads (half the VMEM instructions).
// tmp packed 8B (src|lid|fix22). hw2 64-col bf16 pre-scaled by dinv.
// ---------------------------------------------------------------------------

typedef unsigned short u16;
typedef unsigned long long u64;
typedef __attribute__((ext_vector_type(8))) short short8;
typedef __attribute__((ext_vector_type(4))) float f32x4;

#define FIXSCALE 4194304.0f   // 2^22 fixed-point for deterministic deg
#define HW2S 64               // hw2 row stride (bf16), 40 real + 24 zero pad
#define NSLAB 640             // sort slabs (count/s3 blocks)
#define MAXBUCK 832           // LDS capacity for bucket counters (>= NBUCK)

static __device__ inline u16 f2bf(float f) {            // RNE f32 -> bf16 bits
    unsigned u = __float_as_uint(f);
    return (u16)((u + 0x7fffu + ((u >> 16) & 1u)) >> 16);
}
static __device__ inline float bf2f(u16 h) { return __uint_as_float(((unsigned)h) << 16); }

// pass 1: per-slab bucket histogram (LDS atomics only)
__launch_bounds__(256)
__global__ void k_count(const int* __restrict__ dst, int* __restrict__ cnt1,
                        int E, int EPB, int NBUCK) {
    __shared__ int cnt[MAXBUCK];
    int b = blockIdx.x;
    for (int j = threadIdx.x; j < NBUCK; j += 256) cnt[j] = 0;
    __syncthreads();
    int beg = b * EPB, end = min(beg + EPB, E);
    for (int i = beg + threadIdx.x; i < end; i += 256)
        atomicAdd(&cnt[dst[i] >> 7], 1);
    __syncthreads();
    for (int j = threadIdx.x; j < NBUCK; j += 256)
        cnt1[(size_t)b * NBUCK + j] = cnt[j];
}

// pass 2a: per bucket, exclusive scan over the NSLAB slab counts (in place).
// 782 blocks x 640 threads — strided global I/O but fully latency-hidden.
__launch_bounds__(NSLAB)
__global__ void k_s2a(int* __restrict__ cnt1, int* __restrict__ colTot, int NBUCK) {
    __shared__ int s[NSLAB];
    int j = blockIdx.x;
    int t = threadIdx.x;
    int v = cnt1[(size_t)t * NBUCK + j];
    s[t] = v;
    __syncthreads();
    for (int off = 1; off < NSLAB; off <<= 1) {
        int u = (t >= off) ? s[t - off] : 0;
        __syncthreads();
        s[t] += u;
        __syncthreads();
    }
    cnt1[(size_t)t * NBUCK + j] = s[t] - v;   // exclusive within bucket
    if (t == NSLAB - 1) colTot[j] = s[t];
}

// pass 2b: scan bucket totals -> bucketBase; rowp[N]=E
__launch_bounds__(1024)
__global__ void k_s2b(const int* __restrict__ colTot, int* __restrict__ bucketBase,
                      int* __restrict__ rowp, int NBUCK, int N, int E) {
    __shared__ int s[1024];
    int t = threadIdx.x;
    int v = (t < NBUCK) ? colTot[t] : 0;
    s[t] = v;
    __syncthreads();
    for (int off = 1; off < 1024; off <<= 1) {
        int u = (t >= off) ? s[t - off] : 0;
        __syncthreads();
        s[t] += u;
        __syncthreads();
    }
    if (t < NBUCK) bucketBase[t] = s[t] - v;
    if (t == NBUCK - 1) bucketBase[NBUCK] = s[t];
    if (t == 0) rowp[N] = E;
}

// ---- FAT kernel: [0,gB) gemm1 tiles; [gB,gB+NSLAB) s3 scatter slabs -------
__launch_bounds__(256)
__global__ void k_fat(const float* __restrict__ x, const u16* __restrict__ wt_hi,
                      u16* __restrict__ xw1, int N,
                      const int* __restrict__ src, const int* __restrict__ dst,
                      const float* __restrict__ ew, const int* __restrict__ cnt1,
                      const int* __restrict__ bucketBase, u64* __restrict__ tmp,
                      int E, int gB, int EPB, int NBUCK) {
    __shared__ __align__(16) u16 S[10240];   // 20KB: Ah | Bh, reused by epilogue/s3
    u16* Ah = S;
    u16* Bh = S + 5120;

    if (blockIdx.x >= gB) {
        // ---- s3: scatter packed records to bucket-major tmp (LDS cursors) --
        int* ldsOff = (int*)S;
        int b = blockIdx.x - gB, t = threadIdx.x;
        for (int j = t; j < NBUCK; j += 256)
            ldsOff[j] = bucketBase[j] + cnt1[(size_t)b * NBUCK + j];
        __syncthreads();
        int beg = b * EPB, end = min(beg + EPB, E);
        for (int i = beg + t; i < end; i += 256) {
            int d = dst[i];
            int slot = atomicAdd(&ldsOff[d >> 7], 1);
            unsigned fix = (unsigned)__float2uint_rn(ew[i] * FIXSCALE);  // <= 2^22
            tmp[slot] = ((u64)(unsigned)src[i] << 30) | ((u64)(d & 127) << 23) | fix;
        }
        return;
    }

    // ------- gemm1: MFMA, LDS-staged, register-prefetch pipeline ----------
    const int t = threadIdx.x;
    const int w = t >> 6;
    const int lane = t & 63;
    const int lrow = lane & 15;
    const int q = lane >> 4;
    const int lk = q * 8;
    const int row0 = blockIdx.x * 128;

    int rA[4], cA[4];
    const float* pA[4];
    bool okA[4];
#pragma unroll
    for (int i = 0; i < 4; ++i) {
        int flat = t + i * 256;
        rA[i] = flat >> 3;
        cA[i] = flat & 7;
        int gr = row0 + rA[i];
        okA[i] = gr < N;
        pA[i] = x + (size_t)min(gr, N - 1) * 256 + cA[i] * 4;
    }
    int nB[2], cB[2];
    const u16* pB[2];
#pragma unroll
    for (int i = 0; i < 2; ++i) {
        int flat = t + i * 256;
        nB[i] = flat >> 2;
        cB[i] = flat & 3;
        pB[i] = wt_hi + (size_t)nB[i] * 256 + cB[i] * 8;
    }

    float4 ra[4];
    short8 rb[2];
#pragma unroll
    for (int i = 0; i < 4; ++i)
        ra[i] = okA[i] ? *(const float4*)(pA[i]) : make_float4(0.f, 0.f, 0.f, 0.f);
#pragma unroll
    for (int i = 0; i < 2; ++i) rb[i] = *(const short8*)(pB[i]);

    f32x4 acc[2][8] = {};

    for (int kt = 0; kt < 8; ++kt) {
#pragma unroll
        for (int i = 0; i < 4; ++i) {
            ushort4 vh;
            vh.x = f2bf(ra[i].x);
            vh.y = f2bf(ra[i].y);
            vh.z = f2bf(ra[i].z);
            vh.w = f2bf(ra[i].w);
            *(ushort4*)(Ah + rA[i] * 40 + cA[i] * 4) = vh;
        }
#pragma unroll
        for (int i = 0; i < 2; ++i)
            *(short8*)(Bh + nB[i] * 40 + cB[i] * 8) = rb[i];
        __syncthreads();

        if (kt < 7) {
#pragma unroll
            for (int i = 0; i < 4; ++i)
                ra[i] = okA[i] ? *(const float4*)(pA[i] + (kt + 1) * 32)
                               : make_float4(0.f, 0.f, 0.f, 0.f);
#pragma unroll
            for (int i = 0; i < 2; ++i)
                rb[i] = *(const short8*)(pB[i] + (kt + 1) * 32);
        }

        short8 a0 = *(const short8*)(Ah + (w * 32 + lrow) * 40 + lk);
        short8 a1 = *(const short8*)(Ah + (w * 32 + 16 + lrow) * 40 + lk);
#pragma unroll
        for (int ni = 0; ni < 8; ++ni) {
            short8 bh = *(const short8*)(Bh + (ni * 16 + lrow) * 40 + lk);
            acc[0][ni] = __builtin_amdgcn_mfma_f32_16x16x32_bf16(a0, bh, acc[0][ni], 0, 0, 0);
            acc[1][ni] = __builtin_amdgcn_mfma_f32_16x16x32_bf16(a1, bh, acc[1][ni], 0, 0, 0);
        }
        __syncthreads();
    }

    // ---- epilogue: LDS-bounce transpose -> coalesced 16B stores ----------
#pragma unroll
    for (int mi = 0; mi < 2; ++mi) {
        if (mi) __syncthreads();
#pragma unroll
        for (int r = 0; r < 4; ++r)
#pragma unroll
            for (int ni = 0; ni < 8; ++ni)
                S[(w * 16 + q * 4 + r) * 136 + lrow + ni * 16] = f2bf(acc[mi][ni][r]);
        __syncthreads();
        int l = t >> 2;
        int grow = row0 + (l >> 4) * 32 + mi * 16 + (l & 15);
        if (grow < N) {
#pragma unroll
            for (int c = 0; c < 4; ++c) {
                int col = (t & 3) * 8 + c * 32;
                *(short8*)(xw1 + (size_t)grow * 128 + col) =
                    *(const short8*)(S + l * 136 + col);
            }
        }
    }
}

// pass 4: per bucket (128 nodes): counts+deg (LDS), scan -> rowp/dinv,
// then write entries (src, ew*dinv_dst) to final contiguous slots.
__launch_bounds__(256)
__global__ void k_s4(const u64* __restrict__ tmp, const int* __restrict__ bucketBase,
                     int* __restrict__ rowp, float* __restrict__ dinv,
                     int2* __restrict__ entries, int N) {
    __shared__ int cnt[128];
    __shared__ unsigned degfix[128];
    __shared__ int sc[128];
    __shared__ int nextOff[128];
    __shared__ float dl[128];
    int k = blockIdx.x, t = threadIdx.x;
    int base = bucketBase[k], endb = bucketBase[k + 1];
    if (t < 128) { cnt[t] = 0; degfix[t] = 0; }
    __syncthreads();
    for (int i = base + t; i < endb; i += 256) {
        u64 r = tmp[i];
        int lid = (int)(r >> 23) & 127;
        atomicAdd(&cnt[lid], 1);
        atomicAdd(&degfix[lid], (unsigned)(r & 0x7fffff));
    }
    __syncthreads();
    if (t < 128) sc[t] = cnt[t];
    __syncthreads();
    for (int off = 1; off < 128; off <<= 1) {
        int u = 0;
        if (t < 128 && t >= off) u = sc[t - off];
        __syncthreads();
        if (t < 128) sc[t] += u;
        __syncthreads();
    }
    if (t < 128) {
        int off0 = base + sc[t] - cnt[t];
        nextOff[t] = off0;
        float di = rsqrtf((float)degfix[t] * (1.0f / FIXSCALE) + 1.0f);
        dl[t] = di;
        int gn = k * 128 + t;
        if (gn < N) { rowp[gn] = off0; dinv[gn] = di; }
    }
    __syncthreads();
    for (int i = base + t; i < endb; i += 256) {
        u64 r = tmp[i];
        int lid = (int)(r >> 23) & 127;
        int slot = atomicAdd(&nextOff[lid], 1);
        float ew = (float)(unsigned)(r & 0x7fffff) * (1.0f / FIXSCALE);
        float w = ew * dl[lid];                        // ew * dinv[dst]
        entries[slot] = make_int2((int)(r >> 30), __float_as_int(w));
    }
}

// W1[256,128] f32 -> Wt_hi[128,256] bf16 (transposed)
__global__ void k_wsplit(const float* __restrict__ W1, u16* __restrict__ wt_hi) {
    int idx = blockIdx.x * 256 + threadIdx.x;
    if (idx < 256 * 128) {
        int n = idx & 127, k = idx >> 7;
        wt_hi[n * 256 + k] = f2bf(W1[idx]);
    }
}

// gather layer 1: agg1[n] = dinv^2[n]*xw1[n] + sum_e (w_e*dinv[src_e])*xw1[src_e]
// 16 lanes/node, one 16B short8 per lane, 2-way edge unroll.
__launch_bounds__(256)
__global__ void k_gather1(const u16* __restrict__ xw1, const int2* __restrict__ entries,
                          const int* __restrict__ row, const float* __restrict__ dinv,
                          u16* __restrict__ agg1, int N) {
    int g = (blockIdx.x * 256 + threadIdx.x) >> 4;
    if (g >= N) return;
    int j = (threadIdx.x & 15) * 8;
    float di = dinv[g];
    float d2 = di * di;
    float acc[8];
    {
        short8 sv = *(const short8*)(xw1 + (size_t)g * 128 + j);
#pragma unroll
        for (int k = 0; k < 8; ++k) acc[k] = d2 * bf2f((u16)sv[k]);
    }
    int e = row[g], end = row[g + 1];
    for (; e + 2 <= end; e += 2) {
        int2 e0 = entries[e];
        int2 e1 = entries[e + 1];
        short8 v0 = *(const short8*)(xw1 + (size_t)e0.x * 128 + j);
        short8 v1 = *(const short8*)(xw1 + (size_t)e1.x * 128 + j);
        float w0 = __int_as_float(e0.y) * dinv[e0.x];
        float w1 = __int_as_float(e1.y) * dinv[e1.x];
#pragma unroll
        for (int k = 0; k < 8; ++k)
            acc[k] += w0 * bf2f((u16)v0[k]) + w1 * bf2f((u16)v1[k]);
    }
    if (e < end) {
        int2 e0 = entries[e];
        short8 v0 = *(const short8*)(xw1 + (size_t)e0.x * 128 + j);
        float w0 = __int_as_float(e0.y) * dinv[e0.x];
#pragma unroll
        for (int k = 0; k < 8; ++k) acc[k] += w0 * bf2f((u16)v0[k]);
    }
    short8 o;
#pragma unroll
    for (int k = 0; k < 8; ++k) o[k] = (short)f2bf(acc[k]);
    *(short8*)(agg1 + (size_t)g * 128 + j) = o;
}

// GEMM2: h = relu(agg1 + b1); hw2[N,64](bf16) = dinv[row] * (h @ W2), pad 0
__launch_bounds__(320)
__global__ void k_gemm2(const u16* __restrict__ agg1, const float* __restrict__ W2,
                        const float* __restrict__ b1, const float* __restrict__ dinv,
                        u16* __restrict__ hw2, int N) {
    __shared__ float As[64 * 132];
    __shared__ float Bs[128 * 40];
    const int t = threadIdx.x;
    const int row0 = blockIdx.x * 64;

    for (int flat = t; flat < 128 * 40; flat += 320) Bs[flat] = W2[flat];

#pragma unroll
    for (int i = 0; i < 7; ++i) {
        int flat = t + i * 320;
        if (flat < 2048) {
            int r = flat >> 5, c4 = flat & 31;
            int gr = row0 + r;
            float4 v = make_float4(0.f, 0.f, 0.f, 0.f);
            if (gr < N) {
                ushort4 s = *(const ushort4*)(agg1 + (size_t)gr * 128 + c4 * 4);
                float4 bb = *(const float4*)(b1 + c4 * 4);
                v.x = fmaxf(bf2f(s.x) + bb.x, 0.f);
                v.y = fmaxf(bf2f(s.y) + bb.y, 0.f);
                v.z = fmaxf(bf2f(s.z) + bb.z, 0.f);
                v.w = fmaxf(bf2f(s.w) + bb.w, 0.f);
            }
            *(float4*)(As + r * 132 + c4 * 4) = v;
        }
    }
    __syncthreads();

    const int tx = t % 40;
    const int ty = t / 40;
    float acc[8];
#pragma unroll
    for (int r = 0; r < 8; ++r) acc[r] = 0.f;
    for (int k = 0; k < 128; ++k) {
        float b = Bs[k * 40 + tx];
#pragma unroll
        for (int r = 0; r < 8; ++r) acc[r] += As[(ty * 8 + r) * 132 + k] * b;
    }
#pragma unroll
    for (int r = 0; r < 8; ++r) {
        int gr = row0 + ty * 8 + r;
        if (gr < N) hw2[(size_t)gr * HW2S + tx] = f2bf(dinv[gr] * acc[r]);
    }
    for (int idx = t; idx < 64 * 24; idx += 320) {
        int r = idx / 24, c = 40 + idx % 24;
        int gr = row0 + r;
        if (gr < N) hw2[(size_t)gr * HW2S + c] = 0;
    }
}

// gather layer 2 + bias + fused L2 normalize -> out
__launch_bounds__(256)
__global__ void k_gather2(const u16* __restrict__ hw2, const int2* __restrict__ entries,
                          const int* __restrict__ row, const float* __restrict__ dinv,
                          const float* __restrict__ b2, float* __restrict__ out, int N) {
    int g = (blockIdx.x * 256 + threadIdx.x) >> 3;
    if (g >= N) return;
    int l = threadIdx.x & 7;
    int c0 = l * 8;
    float di = dinv[g];
    float bb[8];
#pragma unroll
    for (int k = 0; k < 8; ++k) bb[k] = (c0 + k < 40) ? b2[c0 + k] : 0.f;

    float acc[8];
    {
        short8 sv = *(const short8*)(hw2 + (size_t)g * HW2S + c0);
#pragma unroll
        for (int k = 0; k < 8; ++k) acc[k] = di * bf2f((u16)sv[k]) + bb[k];
    }
    int e = row[g], end = row[g + 1];
    for (; e + 2 <= end; e += 2) {
        int2 e0 = entries[e];
        int2 e1 = entries[e + 1];
        float w0 = __int_as_float(e0.y);      // ew*dinv[dst]; dinv[src] in hw2
        float w1 = __int_as_float(e1.y);
        short8 v0 = *(const short8*)(hw2 + (size_t)e0.x * HW2S + c0);
        short8 v1 = *(const short8*)(hw2 + (size_t)e1.x * HW2S + c0);
#pragma unroll
        for (int k = 0; k < 8; ++k)
            acc[k] += w0 * bf2f((u16)v0[k]) + w1 * bf2f((u16)v1[k]);
    }
    if (e < end) {
        int2 e0 = entries[e];
        float w0 = __int_as_float(e0.y);
        short8 v0 = *(const short8*)(hw2 + (size_t)e0.x * HW2S + c0);
#pragma unroll
        for (int k = 0; k < 8; ++k) acc[k] += w0 * bf2f((u16)v0[k]);
    }
    float ss = 0.f;
#pragma unroll
    for (int k = 0; k < 8; ++k) ss += acc[k] * acc[k];
    ss += __shfl_xor(ss, 1);
    ss += __shfl_xor(ss, 2);
    ss += __shfl_xor(ss, 4);
    float inv = 1.f / fmaxf(sqrtf(ss), 1e-12f);
    if (l < 5) {
        float* q = out + (size_t)g * 40 + c0;
        *(float4*)(q)     = make_float4(acc[0] * inv, acc[1] * inv, acc[2] * inv, acc[3] * inv);
        *(float4*)(q + 4) = make_float4(acc[4] * inv, acc[5] * inv, acc[6] * inv, acc[7] * inv);
    }
}

extern "C" void kernel_launch(void* const* d_in, const int* in_sizes, int n_in,
                              void* d_out, int out_size, void* d_ws, size_t ws_size,
                              hipStream_t stream) {
    const float* x   = (const float*)d_in[0];
    const int*   ei  = (const int*)d_in[1];
    const float* ew  = (const float*)d_in[2];
    const float* W1  = (const float*)d_in[3];
    const float* b1  = (const float*)d_in[4];
    const float* W2  = (const float*)d_in[5];
    const float* b2  = (const float*)d_in[6];
    float* out = (float*)d_out;

    const int N = in_sizes[0] / 256;   // 100000
    const int E = in_sizes[2];         // 1600000
    const int* src = ei;
    const int* dst = ei + E;
    const int NBUCK = (N + 127) >> 7;  // 782
    const int EPB = (E + NSLAB - 1) / NSLAB;

    char* ws = (char*)d_ws;
    size_t off = 0;
    auto take = [&](size_t bytes) -> void* {
        void* p = (void*)(ws + off);
        off += (bytes + 255) & ~(size_t)255;
        return p;
    };
    int*   cnt1    = (int*)take((size_t)NSLAB * NBUCK * 4);   // 2MB
    int*   colTot  = (int*)take((size_t)NBUCK * 4);
    int*   bucketBase = (int*)take((size_t)(NBUCK + 1) * 4);
    int*   rowp    = (int*)take((size_t)(N + 1) * 4);
    float* dinv    = (float*)take((size_t)N * 4);
    u64*   tmp     = (u64*)take((size_t)E * 8);               // 12.8MB (packed)
    int2*  entries = (int2*)take((size_t)E * 8);              // 12.8MB
    u16*   wt_hi   = (u16*)take((size_t)128 * 256 * 2);
    u16*   xw1     = (u16*)take((size_t)N * 128 * 2);
    u16*   agg1    = (u16*)take((size_t)N * 128 * 2);         // bf16
    u16*   hw2     = (u16*)take((size_t)N * HW2S * 2);        // 12.8MB

    k_wsplit<<<(256 * 128 + 255) / 256, 256, 0, stream>>>(W1, wt_hi);
    k_count<<<NSLAB, 256, 0, stream>>>(dst, cnt1, E, EPB, NBUCK);
    k_s2a<<<NBUCK, NSLAB, 0, stream>>>(cnt1, colTot, NBUCK);
    k_s2b<<<1, 1024, 0, stream>>>(colTot, bucketBase, rowp, NBUCK, N, E);

    const int gB = (N + 127) / 128;           // 782 gemm tiles
    k_fat<<<gB + NSLAB, 256, 0, stream>>>(x, wt_hi, xw1, N,
                                          src, dst, ew, cnt1, bucketBase, tmp,
                                          E, gB, EPB, NBUCK);

    k_s4<<<NBUCK, 256, 0, stream>>>(tmp, bucketBase, rowp, dinv, entries, N);

    k_gather1<<<((size_t)N * 16 + 255) / 256, 256, 0, stream>>>(xw1, entries, rowp, dinv, agg1, N);
    k_gemm2<<<(N + 63) / 64, 320, 0, stream>>>(agg1, W2, b1, dinv, hw2, N);
    k_gather2<<<(N * 8 + 255) / 256, 256, 0, stream>>>(hw2, entries, rowp, dinv, b2, out, N);
}

// Round 22
// 231.171 us; speedup vs baseline: 1.0529x; 1.0071x over previous
//
#include <hip/hip_runtime.h>

// ---------------------------------------------------------------------------
// 2-layer GCN forward (PyG GCNConv, add_self_loops, sym-norm), CSR-gather.
//   dinv = rsqrt(segsum(ew,dst)+1)
//   h    = relu( Agg(norm, x@W1) + dinv^2*(x@W1) + b1 )
//   out  = L2norm( Agg(norm, h@W2) + dinv^2*(h@W2) + b2 )
// CSR build = LDS counting sort (NO global atomics; 74us atomic cap R6-R9).
// Config (R21, best-of-each validated by R15/R16/R20 A/Bs):
//   NSLAB=640 (fat co-schedule), original strided Hillis-Steele s2a,
//   R15 single-buffered 20KB fat with reg-prefetch + LDS-bounce epilogue,
//   agg1 bf16, gather1 = 32 lanes/node (16-lane R20 variant lost ~10us to
//   wave tail-divergence / halved MLP).
// tmp packed 8B (src|lid|fix22). hw2 64-col bf16 pre-scaled by dinv.
// ---------------------------------------------------------------------------

typedef unsigned short u16;
typedef unsigned long long u64;
typedef __attribute__((ext_vector_type(8))) short short8;
typedef __attribute__((ext_vector_type(4))) float f32x4;

#define FIXSCALE 4194304.0f   // 2^22 fixed-point for deterministic deg
#define HW2S 64               // hw2 row stride (bf16), 40 real + 24 zero pad
#define NSLAB 640             // sort slabs (count/s3 blocks)
#define MAXBUCK 832           // LDS capacity for bucket counters (>= NBUCK)

static __device__ inline u16 f2bf(float f) {            // RNE f32 -> bf16 bits
    unsigned u = __float_as_uint(f);
    return (u16)((u + 0x7fffu + ((u >> 16) & 1u)) >> 16);
}
static __device__ inline float bf2f(u16 h) { return __uint_as_float(((unsigned)h) << 16); }

// pass 1: per-slab bucket histogram (LDS atomics only)
__launch_bounds__(256)
__global__ void k_count(const int* __restrict__ dst, int* __restrict__ cnt1,
                        int E, int EPB, int NBUCK) {
    __shared__ int cnt[MAXBUCK];
    int b = blockIdx.x;
    for (int j = threadIdx.x; j < NBUCK; j += 256) cnt[j] = 0;
    __syncthreads();
    int beg = b * EPB, end = min(beg + EPB, E);
    for (int i = beg + threadIdx.x; i < end; i += 256)
        atomicAdd(&cnt[dst[i] >> 7], 1);
    __syncthreads();
    for (int j = threadIdx.x; j < NBUCK; j += 256)
        cnt1[(size_t)b * NBUCK + j] = cnt[j];
}

// pass 2a: per bucket, exclusive scan over the NSLAB slab counts (in place).
// 782 blocks x 640 threads — strided global I/O but fully latency-hidden.
__launch_bounds__(NSLAB)
__global__ void k_s2a(int* __restrict__ cnt1, int* __restrict__ colTot, int NBUCK) {
    __shared__ int s[NSLAB];
    int j = blockIdx.x;
    int t = threadIdx.x;
    int v = cnt1[(size_t)t * NBUCK + j];
    s[t] = v;
    __syncthreads();
    for (int off = 1; off < NSLAB; off <<= 1) {
        int u = (t >= off) ? s[t - off] : 0;
        __syncthreads();
        s[t] += u;
        __syncthreads();
    }
    cnt1[(size_t)t * NBUCK + j] = s[t] - v;   // exclusive within bucket
    if (t == NSLAB - 1) colTot[j] = s[t];
}

// pass 2b: scan bucket totals -> bucketBase; rowp[N]=E
__launch_bounds__(1024)
__global__ void k_s2b(const int* __restrict__ colTot, int* __restrict__ bucketBase,
                      int* __restrict__ rowp, int NBUCK, int N, int E) {
    __shared__ int s[1024];
    int t = threadIdx.x;
    int v = (t < NBUCK) ? colTot[t] : 0;
    s[t] = v;
    __syncthreads();
    for (int off = 1; off < 1024; off <<= 1) {
        int u = (t >= off) ? s[t - off] : 0;
        __syncthreads();
        s[t] += u;
        __syncthreads();
    }
    if (t < NBUCK) bucketBase[t] = s[t] - v;
    if (t == NBUCK - 1) bucketBase[NBUCK] = s[t];
    if (t == 0) rowp[N] = E;
}

// ---- FAT kernel: [0,gB) gemm1 tiles; [gB,gB+NSLAB) s3 scatter slabs -------
__launch_bounds__(256)
__global__ void k_fat(const float* __restrict__ x, const u16* __restrict__ wt_hi,
                      u16* __restrict__ xw1, int N,
                      const int* __restrict__ src, const int* __restrict__ dst,
                      const float* __restrict__ ew, const int* __restrict__ cnt1,
                      const int* __restrict__ bucketBase, u64* __restrict__ tmp,
                      int E, int gB, int EPB, int NBUCK) {
    __shared__ __align__(16) u16 S[10240];   // 20KB: Ah | Bh, reused by epilogue/s3
    u16* Ah = S;
    u16* Bh = S + 5120;

    if (blockIdx.x >= gB) {
        // ---- s3: scatter packed records to bucket-major tmp (LDS cursors) --
        int* ldsOff = (int*)S;
        int b = blockIdx.x - gB, t = threadIdx.x;
        for (int j = t; j < NBUCK; j += 256)
            ldsOff[j] = bucketBase[j] + cnt1[(size_t)b * NBUCK + j];
        __syncthreads();
        int beg = b * EPB, end = min(beg + EPB, E);
        for (int i = beg + t; i < end; i += 256) {
            int d = dst[i];
            int slot = atomicAdd(&ldsOff[d >> 7], 1);
            unsigned fix = (unsigned)__float2uint_rn(ew[i] * FIXSCALE);  // <= 2^22
            tmp[slot] = ((u64)(unsigned)src[i] << 30) | ((u64)(d & 127) << 23) | fix;
        }
        return;
    }

    // ------- gemm1: MFMA, LDS-staged, register-prefetch pipeline ----------
    const int t = threadIdx.x;
    const int w = t >> 6;
    const int lane = t & 63;
    const int lrow = lane & 15;
    const int q = lane >> 4;
    const int lk = q * 8;
    const int row0 = blockIdx.x * 128;

    int rA[4], cA[4];
    const float* pA[4];
    bool okA[4];
#pragma unroll
    for (int i = 0; i < 4; ++i) {
        int flat = t + i * 256;
        rA[i] = flat >> 3;
        cA[i] = flat & 7;
        int gr = row0 + rA[i];
        okA[i] = gr < N;
        pA[i] = x + (size_t)min(gr, N - 1) * 256 + cA[i] * 4;
    }
    int nB[2], cB[2];
    const u16* pB[2];
#pragma unroll
    for (int i = 0; i < 2; ++i) {
        int flat = t + i * 256;
        nB[i] = flat >> 2;
        cB[i] = flat & 3;
        pB[i] = wt_hi + (size_t)nB[i] * 256 + cB[i] * 8;
    }

    float4 ra[4];
    short8 rb[2];
#pragma unroll
    for (int i = 0; i < 4; ++i)
        ra[i] = okA[i] ? *(const float4*)(pA[i]) : make_float4(0.f, 0.f, 0.f, 0.f);
#pragma unroll
    for (int i = 0; i < 2; ++i) rb[i] = *(const short8*)(pB[i]);

    f32x4 acc[2][8] = {};

    for (int kt = 0; kt < 8; ++kt) {
#pragma unroll
        for (int i = 0; i < 4; ++i) {
            ushort4 vh;
            vh.x = f2bf(ra[i].x);
            vh.y = f2bf(ra[i].y);
            vh.z = f2bf(ra[i].z);
            vh.w = f2bf(ra[i].w);
            *(ushort4*)(Ah + rA[i] * 40 + cA[i] * 4) = vh;
        }
#pragma unroll
        for (int i = 0; i < 2; ++i)
            *(short8*)(Bh + nB[i] * 40 + cB[i] * 8) = rb[i];
        __syncthreads();

        if (kt < 7) {
#pragma unroll
            for (int i = 0; i < 4; ++i)
                ra[i] = okA[i] ? *(const float4*)(pA[i] + (kt + 1) * 32)
                               : make_float4(0.f, 0.f, 0.f, 0.f);
#pragma unroll
            for (int i = 0; i < 2; ++i)
                rb[i] = *(const short8*)(pB[i] + (kt + 1) * 32);
        }

        short8 a0 = *(const short8*)(Ah + (w * 32 + lrow) * 40 + lk);
        short8 a1 = *(const short8*)(Ah + (w * 32 + 16 + lrow) * 40 + lk);
#pragma unroll
        for (int ni = 0; ni < 8; ++ni) {
            short8 bh = *(const short8*)(Bh + (ni * 16 + lrow) * 40 + lk);
            acc[0][ni] = __builtin_amdgcn_mfma_f32_16x16x32_bf16(a0, bh, acc[0][ni], 0, 0, 0);
            acc[1][ni] = __builtin_amdgcn_mfma_f32_16x16x32_bf16(a1, bh, acc[1][ni], 0, 0, 0);
        }
        __syncthreads();
    }

    // ---- epilogue: LDS-bounce transpose -> coalesced 16B stores ----------
#pragma unroll
    for (int mi = 0; mi < 2; ++mi) {
        if (mi) __syncthreads();
#pragma unroll
        for (int r = 0; r < 4; ++r)
#pragma unroll
            for (int ni = 0; ni < 8; ++ni)
                S[(w * 16 + q * 4 + r) * 136 + lrow + ni * 16] = f2bf(acc[mi][ni][r]);
        __syncthreads();
        int l = t >> 2;
        int grow = row0 + (l >> 4) * 32 + mi * 16 + (l & 15);
        if (grow < N) {
#pragma unroll
            for (int c = 0; c < 4; ++c) {
                int col = (t & 3) * 8 + c * 32;
                *(short8*)(xw1 + (size_t)grow * 128 + col) =
                    *(const short8*)(S + l * 136 + col);
            }
        }
    }
}

// pass 4: per bucket (128 nodes): counts+deg (LDS), scan -> rowp/dinv,
// then write entries (src, ew*dinv_dst) to final contiguous slots.
__launch_bounds__(256)
__global__ void k_s4(const u64* __restrict__ tmp, const int* __restrict__ bucketBase,
                     int* __restrict__ rowp, float* __restrict__ dinv,
                     int2* __restrict__ entries, int N) {
    __shared__ int cnt[128];
    __shared__ unsigned degfix[128];
    __shared__ int sc[128];
    __shared__ int nextOff[128];
    __shared__ float dl[128];
    int k = blockIdx.x, t = threadIdx.x;
    int base = bucketBase[k], endb = bucketBase[k + 1];
    if (t < 128) { cnt[t] = 0; degfix[t] = 0; }
    __syncthreads();
    for (int i = base + t; i < endb; i += 256) {
        u64 r = tmp[i];
        int lid = (int)(r >> 23) & 127;
        atomicAdd(&cnt[lid], 1);
        atomicAdd(&degfix[lid], (unsigned)(r & 0x7fffff));
    }
    __syncthreads();
    if (t < 128) sc[t] = cnt[t];
    __syncthreads();
    for (int off = 1; off < 128; off <<= 1) {
        int u = 0;
        if (t < 128 && t >= off) u = sc[t - off];
        __syncthreads();
        if (t < 128) sc[t] += u;
        __syncthreads();
    }
    if (t < 128) {
        int off0 = base + sc[t] - cnt[t];
        nextOff[t] = off0;
        float di = rsqrtf((float)degfix[t] * (1.0f / FIXSCALE) + 1.0f);
        dl[t] = di;
        int gn = k * 128 + t;
        if (gn < N) { rowp[gn] = off0; dinv[gn] = di; }
    }
    __syncthreads();
    for (int i = base + t; i < endb; i += 256) {
        u64 r = tmp[i];
        int lid = (int)(r >> 23) & 127;
        int slot = atomicAdd(&nextOff[lid], 1);
        float ew = (float)(unsigned)(r & 0x7fffff) * (1.0f / FIXSCALE);
        float w = ew * dl[lid];                        // ew * dinv[dst]
        entries[slot] = make_int2((int)(r >> 30), __float_as_int(w));
    }
}

// W1[256,128] f32 -> Wt_hi[128,256] bf16 (transposed)
__global__ void k_wsplit(const float* __restrict__ W1, u16* __restrict__ wt_hi) {
    int idx = blockIdx.x * 256 + threadIdx.x;
    if (idx < 256 * 128) {
        int n = idx & 127, k = idx >> 7;
        wt_hi[n * 256 + k] = f2bf(W1[idx]);
    }
}

// gather layer 1: agg1[n] = dinv^2[n]*xw1[n] + sum_e (w_e*dinv[src_e])*xw1[src_e]
// 32 lanes/node (2 nodes/wave: best tail-divergence + MLP), 4-way edge unroll.
__launch_bounds__(256)
__global__ void k_gather1(const u16* __restrict__ xw1, const int2* __restrict__ entries,
                          const int* __restrict__ row, const float* __restrict__ dinv,
                          u16* __restrict__ agg1, int N) {
    int g = (blockIdx.x * 256 + threadIdx.x) >> 5;
    if (g >= N) return;
    int j = (threadIdx.x & 31) * 4;
    float di = dinv[g];
    float d2 = di * di;
    ushort4 sv = *(const ushort4*)(xw1 + (size_t)g * 128 + j);
    float4 acc = make_float4(d2 * bf2f(sv.x), d2 * bf2f(sv.y),
                             d2 * bf2f(sv.z), d2 * bf2f(sv.w));
    int e = row[g], end = row[g + 1];
    for (; e + 4 <= end; e += 4) {
        int2 e0 = entries[e];
        int2 e1 = entries[e + 1];
        int2 e2 = entries[e + 2];
        int2 e3 = entries[e + 3];
        ushort4 v0 = *(const ushort4*)(xw1 + (size_t)e0.x * 128 + j);
        ushort4 v1 = *(const ushort4*)(xw1 + (size_t)e1.x * 128 + j);
        ushort4 v2 = *(const ushort4*)(xw1 + (size_t)e2.x * 128 + j);
        ushort4 v3 = *(const ushort4*)(xw1 + (size_t)e3.x * 128 + j);
        float w0 = __int_as_float(e0.y) * dinv[e0.x];
        float w1 = __int_as_float(e1.y) * dinv[e1.x];
        float w2 = __int_as_float(e2.y) * dinv[e2.x];
        float w3 = __int_as_float(e3.y) * dinv[e3.x];
        acc.x += w0 * bf2f(v0.x) + w1 * bf2f(v1.x) + w2 * bf2f(v2.x) + w3 * bf2f(v3.x);
        acc.y += w0 * bf2f(v0.y) + w1 * bf2f(v1.y) + w2 * bf2f(v2.y) + w3 * bf2f(v3.y);
        acc.z += w0 * bf2f(v0.z) + w1 * bf2f(v1.z) + w2 * bf2f(v2.z) + w3 * bf2f(v3.z);
        acc.w += w0 * bf2f(v0.w) + w1 * bf2f(v1.w) + w2 * bf2f(v2.w) + w3 * bf2f(v3.w);
    }
    for (; e < end; ++e) {
        int2 e0 = entries[e];
        ushort4 v0 = *(const ushort4*)(xw1 + (size_t)e0.x * 128 + j);
        float w0 = __int_as_float(e0.y) * dinv[e0.x];
        acc.x += w0 * bf2f(v0.x);
        acc.y += w0 * bf2f(v0.y);
        acc.z += w0 * bf2f(v0.z);
        acc.w += w0 * bf2f(v0.w);
    }
    ushort4 o;
    o.x = f2bf(acc.x);
    o.y = f2bf(acc.y);
    o.z = f2bf(acc.z);
    o.w = f2bf(acc.w);
    *(ushort4*)(agg1 + (size_t)g * 128 + j) = o;
}

// GEMM2: h = relu(agg1 + b1); hw2[N,64](bf16) = dinv[row] * (h @ W2), pad 0
__launch_bounds__(320)
__global__ void k_gemm2(const u16* __restrict__ agg1, const float* __restrict__ W2,
                        const float* __restrict__ b1, const float* __restrict__ dinv,
                        u16* __restrict__ hw2, int N) {
    __shared__ float As[64 * 132];
    __shared__ float Bs[128 * 40];
    const int t = threadIdx.x;
    const int row0 = blockIdx.x * 64;

    for (int flat = t; flat < 128 * 40; flat += 320) Bs[flat] = W2[flat];

#pragma unroll
    for (int i = 0; i < 7; ++i) {
        int flat = t + i * 320;
        if (flat < 2048) {
            int r = flat >> 5, c4 = flat & 31;
            int gr = row0 + r;
            float4 v = make_float4(0.f, 0.f, 0.f, 0.f);
            if (gr < N) {
                ushort4 s = *(const ushort4*)(agg1 + (size_t)gr * 128 + c4 * 4);
                float4 bb = *(const float4*)(b1 + c4 * 4);
                v.x = fmaxf(bf2f(s.x) + bb.x, 0.f);
                v.y = fmaxf(bf2f(s.y) + bb.y, 0.f);
                v.z = fmaxf(bf2f(s.z) + bb.z, 0.f);
                v.w = fmaxf(bf2f(s.w) + bb.w, 0.f);
            }
            *(float4*)(As + r * 132 + c4 * 4) = v;
        }
    }
    __syncthreads();

    const int tx = t % 40;
    const int ty = t / 40;
    float acc[8];
#pragma unroll
    for (int r = 0; r < 8; ++r) acc[r] = 0.f;
    for (int k = 0; k < 128; ++k) {
        float b = Bs[k * 40 + tx];
#pragma unroll
        for (int r = 0; r < 8; ++r) acc[r] += As[(ty * 8 + r) * 132 + k] * b;
    }
#pragma unroll
    for (int r = 0; r < 8; ++r) {
        int gr = row0 + ty * 8 + r;
        if (gr < N) hw2[(size_t)gr * HW2S + tx] = f2bf(dinv[gr] * acc[r]);
    }
    for (int idx = t; idx < 64 * 24; idx += 320) {
        int r = idx / 24, c = 40 + idx % 24;
        int gr = row0 + r;
        if (gr < N) hw2[(size_t)gr * HW2S + c] = 0;
    }
}

// gather layer 2 + bias + fused L2 normalize -> out
__launch_bounds__(256)
__global__ void k_gather2(const u16* __restrict__ hw2, const int2* __restrict__ entries,
                          const int* __restrict__ row, const float* __restrict__ dinv,
                          const float* __restrict__ b2, float* __restrict__ out, int N) {
    int g = (blockIdx.x * 256 + threadIdx.x) >> 3;
    if (g >= N) return;
    int l = threadIdx.x & 7;
    int c0 = l * 8;
    float di = dinv[g];
    float bb[8];
#pragma unroll
    for (int k = 0; k < 8; ++k) bb[k] = (c0 + k < 40) ? b2[c0 + k] : 0.f;

    float acc[8];
    {
        short8 sv = *(const short8*)(hw2 + (size_t)g * HW2S + c0);
#pragma unroll
        for (int k = 0; k < 8; ++k) acc[k] = di * bf2f((u16)sv[k]) + bb[k];
    }
    int e = row[g], end = row[g + 1];
    for (; e + 2 <= end; e += 2) {
        int2 e0 = entries[e];
        int2 e1 = entries[e + 1];
        float w0 = __int_as_float(e0.y);      // ew*dinv[dst]; dinv[src] in hw2
        float w1 = __int_as_float(e1.y);
        short8 v0 = *(const short8*)(hw2 + (size_t)e0.x * HW2S + c0);
        short8 v1 = *(const short8*)(hw2 + (size_t)e1.x * HW2S + c0);
#pragma unroll
        for (int k = 0; k < 8; ++k)
            acc[k] += w0 * bf2f((u16)v0[k]) + w1 * bf2f((u16)v1[k]);
    }
    if (e < end) {
        int2 e0 = entries[e];
        float w0 = __int_as_float(e0.y);
        short8 v0 = *(const short8*)(hw2 + (size_t)e0.x * HW2S + c0);
#pragma unroll
        for (int k = 0; k < 8; ++k) acc[k] += w0 * bf2f((u16)v0[k]);
    }
    float ss = 0.f;
#pragma unroll
    for (int k = 0; k < 8; ++k) ss += acc[k] * acc[k];
    ss += __shfl_xor(ss, 1);
    ss += __shfl_xor(ss, 2);
    ss += __shfl_xor(ss, 4);
    float inv = 1.f / fmaxf(sqrtf(ss), 1e-12f);
    if (l < 5) {
        float* q = out + (size_t)g * 40 + c0;
        *(float4*)(q)     = make_float4(acc[0] * inv, acc[1] * inv, acc[2] * inv, acc[3] * inv);
        *(float4*)(q + 4) = make_float4(acc[4] * inv, acc[5] * inv, acc[6] * inv, acc[7] * inv);
    }
}

extern "C" void kernel_launch(void* const* d_in, const int* in_sizes, int n_in,
                              void* d_out, int out_size, void* d_ws, size_t ws_size,
                              hipStream_t stream) {
    const float* x   = (const float*)d_in[0];
    const int*   ei  = (const int*)d_in[1];
    const float* ew  = (const float*)d_in[2];
    const float* W1  = (const float*)d_in[3];
    const float* b1  = (const float*)d_in[4];
    const float* W2  = (const float*)d_in[5];
    const float* b2  = (const float*)d_in[6];
    float* out = (float*)d_out;

    const int N = in_sizes[0] / 256;   // 100000
    const int E = in_sizes[2];         // 1600000
    const int* src = ei;
    const int* dst = ei + E;
    const int NBUCK = (N + 127) >> 7;  // 782
    const int EPB = (E + NSLAB - 1) / NSLAB;

    char* ws = (char*)d_ws;
    size_t off = 0;
    auto take = [&](size_t bytes) -> void* {
        void* p = (void*)(ws + off);
        off += (bytes + 255) & ~(size_t)255;
        return p;
    };
    int*   cnt1    = (int*)take((size_t)NSLAB * NBUCK * 4);   // 2MB
    int*   colTot  = (int*)take((size_t)NBUCK * 4);
    int*   bucketBase = (int*)take((size_t)(NBUCK + 1) * 4);
    int*   rowp    = (int*)take((size_t)(N + 1) * 4);
    float* dinv    = (float*)take((size_t)N * 4);
    u64*   tmp     = (u64*)take((size_t)E * 8);               // 12.8MB (packed)
    int2*  entries = (int2*)take((size_t)E * 8);              // 12.8MB
    u16*   wt_hi   = (u16*)take((size_t)128 * 256 * 2);
    u16*   xw1     = (u16*)take((size_t)N * 128 * 2);
    u16*   agg1    = (u16*)take((size_t)N * 128 * 2);         // bf16
    u16*   hw2     = (u16*)take((size_t)N * HW2S * 2);        // 12.8MB

    k_wsplit<<<(256 * 128 + 255) / 256, 256, 0, stream>>>(W1, wt_hi);
    k_count<<<NSLAB, 256, 0, stream>>>(dst, cnt1, E, EPB, NBUCK);
    k_s2a<<<NBUCK, NSLAB, 0, stream>>>(cnt1, colTot, NBUCK);
    k_s2b<<<1, 1024, 0, stream>>>(colTot, bucketBase, rowp, NBUCK, N, E);

    const int gB = (N + 127) / 128;           // 782 gemm tiles
    k_fat<<<gB + NSLAB, 256, 0, stream>>>(x, wt_hi, xw1, N,
                                          src, dst, ew, cnt1, bucketBase, tmp,
                                          E, gB, EPB, NBUCK);

    k_s4<<<NBUCK, 256, 0, stream>>>(tmp, bucketBase, rowp, dinv, entries, N);

    k_gather1<<<((size_t)N * 32 + 255) / 256, 256, 0, stream>>>(xw1, entries, rowp, dinv, agg1, N);
    k_gemm2<<<(N + 63) / 64, 320, 0, stream>>>(agg1, W2, b1, dinv, hw2, N);
    k_gather2<<<(N * 8 + 255) / 256, 256, 0, stream>>>(hw2, entries, rowp, dinv, b2, out, N);
}

// Round 23
// 227.330 us; speedup vs baseline: 1.0707x; 1.0169x over previous
//
#include <hip/hip_runtime.h>

// ---------------------------------------------------------------------------
// 2-layer GCN forward (PyG GCNConv, add_self_loops, sym-norm), CSR-gather.
//   dinv = rsqrt(segsum(ew,dst)+1)
//   h    = relu( Agg(norm, x@W1) + dinv^2*(x@W1) + b1 )
//   out  = L2norm( Agg(norm, h@W2) + dinv^2*(h@W2) + b2 )
// CSR build = LDS counting sort (NO global atomics; 74us atomic cap R6-R9).
// Schedule: count -> s2a/s2b -> FAT(gemm1 || s3 scatter) -> s4.
// FINAL = R16 config (best measured, 228.3us): NSLAB=384; original strided
// Hillis-Steele s2a (TLP hides the stride; all "fixes" regressed); R15
// single-buffered 20KB fat w/ reg-prefetch + LDS-bounce epilogue; agg1 bf16;
// gather1 32 lanes/node. tmp packed 8B (src|lid|fix22). hw2 64-col bf16
// pre-scaled by dinv[row].
// ---------------------------------------------------------------------------

typedef unsigned short u16;
typedef unsigned long long u64;
typedef __attribute__((ext_vector_type(8))) short short8;
typedef __attribute__((ext_vector_type(4))) float f32x4;

#define FIXSCALE 4194304.0f   // 2^22 fixed-point for deterministic deg
#define HW2S 64               // hw2 row stride (bf16), 40 real + 24 zero pad
#define NSLAB 384             // sort slabs (count/s3 blocks)
#define MAXBUCK 832           // LDS capacity for bucket counters (>= NBUCK)

static __device__ inline u16 f2bf(float f) {            // RNE f32 -> bf16 bits
    unsigned u = __float_as_uint(f);
    return (u16)((u + 0x7fffu + ((u >> 16) & 1u)) >> 16);
}
static __device__ inline float bf2f(u16 h) { return __uint_as_float(((unsigned)h) << 16); }

// pass 1: per-slab bucket histogram (LDS atomics only)
__launch_bounds__(256)
__global__ void k_count(const int* __restrict__ dst, int* __restrict__ cnt1,
                        int E, int EPB, int NBUCK) {
    __shared__ int cnt[MAXBUCK];
    int b = blockIdx.x;
    for (int j = threadIdx.x; j < NBUCK; j += 256) cnt[j] = 0;
    __syncthreads();
    int beg = b * EPB, end = min(beg + EPB, E);
    for (int i = beg + threadIdx.x; i < end; i += 256)
        atomicAdd(&cnt[dst[i] >> 7], 1);
    __syncthreads();
    for (int j = threadIdx.x; j < NBUCK; j += 256)
        cnt1[(size_t)b * NBUCK + j] = cnt[j];
}

// pass 2a: per bucket, exclusive scan over the NSLAB slab counts (in place)
__launch_bounds__(NSLAB)
__global__ void k_s2a(int* __restrict__ cnt1, int* __restrict__ colTot, int NBUCK) {
    __shared__ int s[NSLAB];
    int j = blockIdx.x;
    int t = threadIdx.x;
    int v = cnt1[(size_t)t * NBUCK + j];
    s[t] = v;
    __syncthreads();
    for (int off = 1; off < NSLAB; off <<= 1) {
        int u = (t >= off) ? s[t - off] : 0;
        __syncthreads();
        s[t] += u;
        __syncthreads();
    }
    cnt1[(size_t)t * NBUCK + j] = s[t] - v;   // exclusive within bucket
    if (t == NSLAB - 1) colTot[j] = s[t];
}

// pass 2b: scan bucket totals -> bucketBase; rowp[N]=E
__launch_bounds__(1024)
__global__ void k_s2b(const int* __restrict__ colTot, int* __restrict__ bucketBase,
                      int* __restrict__ rowp, int NBUCK, int N, int E) {
    __shared__ int s[1024];
    int t = threadIdx.x;
    int v = (t < NBUCK) ? colTot[t] : 0;
    s[t] = v;
    __syncthreads();
    for (int off = 1; off < 1024; off <<= 1) {
        int u = (t >= off) ? s[t - off] : 0;
        __syncthreads();
        s[t] += u;
        __syncthreads();
    }
    if (t < NBUCK) bucketBase[t] = s[t] - v;
    if (t == NBUCK - 1) bucketBase[NBUCK] = s[t];
    if (t == 0) rowp[N] = E;
}

// ---- FAT kernel: [0,gB) gemm1 tiles; [gB,gB+NSLAB) s3 scatter slabs -------
__launch_bounds__(256)
__global__ void k_fat(const float* __restrict__ x, const u16* __restrict__ wt_hi,
                      u16* __restrict__ xw1, int N,
                      const int* __restrict__ src, const int* __restrict__ dst,
                      const float* __restrict__ ew, const int* __restrict__ cnt1,
                      const int* __restrict__ bucketBase, u64* __restrict__ tmp,
                      int E, int gB, int EPB, int NBUCK) {
    __shared__ __align__(16) u16 S[10240];   // 20KB: Ah | Bh, reused by epilogue/s3
    u16* Ah = S;
    u16* Bh = S + 5120;

    if (blockIdx.x >= gB) {
        // ---- s3: scatter packed records to bucket-major tmp (LDS cursors) --
        int* ldsOff = (int*)S;
        int b = blockIdx.x - gB, t = threadIdx.x;
        for (int j = t; j < NBUCK; j += 256)
            ldsOff[j] = bucketBase[j] + cnt1[(size_t)b * NBUCK + j];
        __syncthreads();
        int beg = b * EPB, end = min(beg + EPB, E);
        for (int i = beg + t; i < end; i += 256) {
            int d = dst[i];
            int slot = atomicAdd(&ldsOff[d >> 7], 1);
            unsigned fix = (unsigned)__float2uint_rn(ew[i] * FIXSCALE);  // <= 2^22
            tmp[slot] = ((u64)(unsigned)src[i] << 30) | ((u64)(d & 127) << 23) | fix;
        }
        return;
    }

    // ------- gemm1: MFMA, LDS-staged, register-prefetch pipeline ----------
    const int t = threadIdx.x;
    const int w = t >> 6;
    const int lane = t & 63;
    const int lrow = lane & 15;
    const int q = lane >> 4;
    const int lk = q * 8;
    const int row0 = blockIdx.x * 128;

    int rA[4], cA[4];
    const float* pA[4];
    bool okA[4];
#pragma unroll
    for (int i = 0; i < 4; ++i) {
        int flat = t + i * 256;
        rA[i] = flat >> 3;
        cA[i] = flat & 7;
        int gr = row0 + rA[i];
        okA[i] = gr < N;
        pA[i] = x + (size_t)min(gr, N - 1) * 256 + cA[i] * 4;
    }
    int nB[2], cB[2];
    const u16* pB[2];
#pragma unroll
    for (int i = 0; i < 2; ++i) {
        int flat = t + i * 256;
        nB[i] = flat >> 2;
        cB[i] = flat & 3;
        pB[i] = wt_hi + (size_t)nB[i] * 256 + cB[i] * 8;
    }

    float4 ra[4];
    short8 rb[2];
#pragma unroll
    for (int i = 0; i < 4; ++i)
        ra[i] = okA[i] ? *(const float4*)(pA[i]) : make_float4(0.f, 0.f, 0.f, 0.f);
#pragma unroll
    for (int i = 0; i < 2; ++i) rb[i] = *(const short8*)(pB[i]);

    f32x4 acc[2][8] = {};

    for (int kt = 0; kt < 8; ++kt) {
#pragma unroll
        for (int i = 0; i < 4; ++i) {
            ushort4 vh;
            vh.x = f2bf(ra[i].x);
            vh.y = f2bf(ra[i].y);
            vh.z = f2bf(ra[i].z);
            vh.w = f2bf(ra[i].w);
            *(ushort4*)(Ah + rA[i] * 40 + cA[i] * 4) = vh;
        }
#pragma unroll
        for (int i = 0; i < 2; ++i)
            *(short8*)(Bh + nB[i] * 40 + cB[i] * 8) = rb[i];
        __syncthreads();

        if (kt < 7) {
#pragma unroll
            for (int i = 0; i < 4; ++i)
                ra[i] = okA[i] ? *(const float4*)(pA[i] + (kt + 1) * 32)
                               : make_float4(0.f, 0.f, 0.f, 0.f);
#pragma unroll
            for (int i = 0; i < 2; ++i)
                rb[i] = *(const short8*)(pB[i] + (kt + 1) * 32);
        }

        short8 a0 = *(const short8*)(Ah + (w * 32 + lrow) * 40 + lk);
        short8 a1 = *(const short8*)(Ah + (w * 32 + 16 + lrow) * 40 + lk);
#pragma unroll
        for (int ni = 0; ni < 8; ++ni) {
            short8 bh = *(const short8*)(Bh + (ni * 16 + lrow) * 40 + lk);
            acc[0][ni] = __builtin_amdgcn_mfma_f32_16x16x32_bf16(a0, bh, acc[0][ni], 0, 0, 0);
            acc[1][ni] = __builtin_amdgcn_mfma_f32_16x16x32_bf16(a1, bh, acc[1][ni], 0, 0, 0);
        }
        __syncthreads();
    }

    // ---- epilogue: LDS-bounce transpose -> coalesced 16B stores ----------
#pragma unroll
    for (int mi = 0; mi < 2; ++mi) {
        if (mi) __syncthreads();
#pragma unroll
        for (int r = 0; r < 4; ++r)
#pragma unroll
            for (int ni = 0; ni < 8; ++ni)
                S[(w * 16 + q * 4 + r) * 136 + lrow + ni * 16] = f2bf(acc[mi][ni][r]);
        __syncthreads();
        int l = t >> 2;
        int grow = row0 + (l >> 4) * 32 + mi * 16 + (l & 15);
        if (grow < N) {
#pragma unroll
            for (int c = 0; c < 4; ++c) {
                int col = (t & 3) * 8 + c * 32;
                *(short8*)(xw1 + (size_t)grow * 128 + col) =
                    *(const short8*)(S + l * 136 + col);
            }
        }
    }
}

// pass 4: per bucket (128 nodes): counts+deg (LDS), scan -> rowp/dinv,
// then write entries (src, ew*dinv_dst) to final contiguous slots.
__launch_bounds__(256)
__global__ void k_s4(const u64* __restrict__ tmp, const int* __restrict__ bucketBase,
                     int* __restrict__ rowp, float* __restrict__ dinv,
                     int2* __restrict__ entries, int N) {
    __shared__ int cnt[128];
    __shared__ unsigned degfix[128];
    __shared__ int sc[128];
    __shared__ int nextOff[128];
    __shared__ float dl[128];
    int k = blockIdx.x, t = threadIdx.x;
    int base = bucketBase[k], endb = bucketBase[k + 1];
    if (t < 128) { cnt[t] = 0; degfix[t] = 0; }
    __syncthreads();
    for (int i = base + t; i < endb; i += 256) {
        u64 r = tmp[i];
        int lid = (int)(r >> 23) & 127;
        atomicAdd(&cnt[lid], 1);
        atomicAdd(&degfix[lid], (unsigned)(r & 0x7fffff));
    }
    __syncthreads();
    if (t < 128) sc[t] = cnt[t];
    __syncthreads();
    for (int off = 1; off < 128; off <<= 1) {
        int u = 0;
        if (t < 128 && t >= off) u = sc[t - off];
        __syncthreads();
        if (t < 128) sc[t] += u;
        __syncthreads();
    }
    if (t < 128) {
        int off0 = base + sc[t] - cnt[t];
        nextOff[t] = off0;
        float di = rsqrtf((float)degfix[t] * (1.0f / FIXSCALE) + 1.0f);
        dl[t] = di;
        int gn = k * 128 + t;
        if (gn < N) { rowp[gn] = off0; dinv[gn] = di; }
    }
    __syncthreads();
    for (int i = base + t; i < endb; i += 256) {
        u64 r = tmp[i];
        int lid = (int)(r >> 23) & 127;
        int slot = atomicAdd(&nextOff[lid], 1);
        float ew = (float)(unsigned)(r & 0x7fffff) * (1.0f / FIXSCALE);
        float w = ew * dl[lid];                        // ew * dinv[dst]
        entries[slot] = make_int2((int)(r >> 30), __float_as_int(w));
    }
}

// W1[256,128] f32 -> Wt_hi[128,256] bf16 (transposed)
__global__ void k_wsplit(const float* __restrict__ W1, u16* __restrict__ wt_hi) {
    int idx = blockIdx.x * 256 + threadIdx.x;
    if (idx < 256 * 128) {
        int n = idx & 127, k = idx >> 7;
        wt_hi[n * 256 + k] = f2bf(W1[idx]);
    }
}

// gather layer 1: agg1[n] = dinv^2[n]*xw1[n] + sum_e (w_e*dinv[src_e])*xw1[src_e]
// 32 lanes/node, 4-way edge unroll; agg1 stored bf16.
__launch_bounds__(256)
__global__ void k_gather1(const u16* __restrict__ xw1, const int2* __restrict__ entries,
                          const int* __restrict__ row, const float* __restrict__ dinv,
                          u16* __restrict__ agg1, int N) {
    int g = (blockIdx.x * 256 + threadIdx.x) >> 5;
    if (g >= N) return;
    int j = (threadIdx.x & 31) * 4;
    float di = dinv[g];
    float d2 = di * di;
    ushort4 sv = *(const ushort4*)(xw1 + (size_t)g * 128 + j);
    float4 acc = make_float4(d2 * bf2f(sv.x), d2 * bf2f(sv.y),
                             d2 * bf2f(sv.z), d2 * bf2f(sv.w));
    int e = row[g], end = row[g + 1];
    for (; e + 4 <= end; e += 4) {
        int2 e0 = entries[e];
        int2 e1 = entries[e + 1];
        int2 e2 = entries[e + 2];
        int2 e3 = entries[e + 3];
        ushort4 v0 = *(const ushort4*)(xw1 + (size_t)e0.x * 128 + j);
        ushort4 v1 = *(const ushort4*)(xw1 + (size_t)e1.x * 128 + j);
        ushort4 v2 = *(const ushort4*)(xw1 + (size_t)e2.x * 128 + j);
        ushort4 v3 = *(const ushort4*)(xw1 + (size_t)e3.x * 128 + j);
        float w0 = __int_as_float(e0.y) * dinv[e0.x];
        float w1 = __int_as_float(e1.y) * dinv[e1.x];
        float w2 = __int_as_float(e2.y) * dinv[e2.x];
        float w3 = __int_as_float(e3.y) * dinv[e3.x];
        acc.x += w0 * bf2f(v0.x) + w1 * bf2f(v1.x) + w2 * bf2f(v2.x) + w3 * bf2f(v3.x);
        acc.y += w0 * bf2f(v0.y) + w1 * bf2f(v1.y) + w2 * bf2f(v2.y) + w3 * bf2f(v3.y);
        acc.z += w0 * bf2f(v0.z) + w1 * bf2f(v1.z) + w2 * bf2f(v2.z) + w3 * bf2f(v3.z);
        acc.w += w0 * bf2f(v0.w) + w1 * bf2f(v1.w) + w2 * bf2f(v2.w) + w3 * bf2f(v3.w);
    }
    for (; e < end; ++e) {
        int2 e0 = entries[e];
        ushort4 v0 = *(const ushort4*)(xw1 + (size_t)e0.x * 128 + j);
        float w0 = __int_as_float(e0.y) * dinv[e0.x];
        acc.x += w0 * bf2f(v0.x);
        acc.y += w0 * bf2f(v0.y);
        acc.z += w0 * bf2f(v0.z);
        acc.w += w0 * bf2f(v0.w);
    }
    ushort4 o;
    o.x = f2bf(acc.x);
    o.y = f2bf(acc.y);
    o.z = f2bf(acc.z);
    o.w = f2bf(acc.w);
    *(ushort4*)(agg1 + (size_t)g * 128 + j) = o;
}

// GEMM2: h = relu(agg1 + b1); hw2[N,64](bf16) = dinv[row] * (h @ W2), pad 0
__launch_bounds__(320)
__global__ void k_gemm2(const u16* __restrict__ agg1, const float* __restrict__ W2,
                        const float* __restrict__ b1, const float* __restrict__ dinv,
                        u16* __restrict__ hw2, int N) {
    __shared__ float As[64 * 132];
    __shared__ float Bs[128 * 40];
    const int t = threadIdx.x;
    const int row0 = blockIdx.x * 64;

    for (int flat = t; flat < 128 * 40; flat += 320) Bs[flat] = W2[flat];

#pragma unroll
    for (int i = 0; i < 7; ++i) {
        int flat = t + i * 320;
        if (flat < 2048) {
            int r = flat >> 5, c4 = flat & 31;
            int gr = row0 + r;
            float4 v = make_float4(0.f, 0.f, 0.f, 0.f);
            if (gr < N) {
                ushort4 s = *(const ushort4*)(agg1 + (size_t)gr * 128 + c4 * 4);
                float4 bb = *(const float4*)(b1 + c4 * 4);
                v.x = fmaxf(bf2f(s.x) + bb.x, 0.f);
                v.y = fmaxf(bf2f(s.y) + bb.y, 0.f);
                v.z = fmaxf(bf2f(s.z) + bb.z, 0.f);
                v.w = fmaxf(bf2f(s.w) + bb.w, 0.f);
            }
            *(float4*)(As + r * 132 + c4 * 4) = v;
        }
    }
    __syncthreads();

    const int tx = t % 40;
    const int ty = t / 40;
    float acc[8];
#pragma unroll
    for (int r = 0; r < 8; ++r) acc[r] = 0.f;
    for (int k = 0; k < 128; ++k) {
        float b = Bs[k * 40 + tx];
#pragma unroll
        for (int r = 0; r < 8; ++r) acc[r] += As[(ty * 8 + r) * 132 + k] * b;
    }
#pragma unroll
    for (int r = 0; r < 8; ++r) {
        int gr = row0 + ty * 8 + r;
        if (gr < N) hw2[(size_t)gr * HW2S + tx] = f2bf(dinv[gr] * acc[r]);
    }
    // zero pad cols 40..63 for all 64 rows
    for (int idx = t; idx < 64 * 24; idx += 320) {
        int r = idx / 24, c = 40 + idx % 24;
        int gr = row0 + r;
        if (gr < N) hw2[(size_t)gr * HW2S + c] = 0;
    }
}

// gather layer 2 + bias + fused L2 normalize -> out
// hw2 rows pre-scaled by dinv[row]; 8 lanes/node, 16B short8 loads.
__launch_bounds__(256)
__global__ void k_gather2(const u16* __restrict__ hw2, const int2* __restrict__ entries,
                          const int* __restrict__ row, const float* __restrict__ dinv,
                          const float* __restrict__ b2, float* __restrict__ out, int N) {
    int g = (blockIdx.x * 256 + threadIdx.x) >> 3;
    if (g >= N) return;
    int l = threadIdx.x & 7;
    int c0 = l * 8;
    float di = dinv[g];
    float bb[8];
#pragma unroll
    for (int k = 0; k < 8; ++k) bb[k] = (c0 + k < 40) ? b2[c0 + k] : 0.f;

    float acc[8];
    {
        short8 sv = *(const short8*)(hw2 + (size_t)g * HW2S + c0);
#pragma unroll
        for (int k = 0; k < 8; ++k) acc[k] = di * bf2f((u16)sv[k]) + bb[k];
    }
    int e = row[g], end = row[g + 1];
    for (; e + 2 <= end; e += 2) {
        int2 e0 = entries[e];
        int2 e1 = entries[e + 1];
        float w0 = __int_as_float(e0.y);      // ew*dinv[dst]; dinv[src] in hw2
        float w1 = __int_as_float(e1.y);
        short8 v0 = *(const short8*)(hw2 + (size_t)e0.x * HW2S + c0);
        short8 v1 = *(const short8*)(hw2 + (size_t)e1.x * HW2S + c0);
#pragma unroll
        for (int k = 0; k < 8; ++k)
            acc[k] += w0 * bf2f((u16)v0[k]) + w1 * bf2f((u16)v1[k]);
    }
    if (e < end) {
        int2 e0 = entries[e];
        float w0 = __int_as_float(e0.y);
        short8 v0 = *(const short8*)(hw2 + (size_t)e0.x * HW2S + c0);
#pragma unroll
        for (int k = 0; k < 8; ++k) acc[k] += w0 * bf2f((u16)v0[k]);
    }
    float ss = 0.f;
#pragma unroll
    for (int k = 0; k < 8; ++k) ss += acc[k] * acc[k];
    ss += __shfl_xor(ss, 1);
    ss += __shfl_xor(ss, 2);
    ss += __shfl_xor(ss, 4);
    float inv = 1.f / fmaxf(sqrtf(ss), 1e-12f);
    if (l < 5) {
        float* q = out + (size_t)g * 40 + c0;
        *(float4*)(q)     = make_float4(acc[0] * inv, acc[1] * inv, acc[2] * inv, acc[3] * inv);
        *(float4*)(q + 4) = make_float4(acc[4] * inv, acc[5] * inv, acc[6] * inv, acc[7] * inv);
    }
}

extern "C" void kernel_launch(void* const* d_in, const int* in_sizes, int n_in,
                              void* d_out, int out_size, void* d_ws, size_t ws_size,
                              hipStream_t stream) {
    const float* x   = (const float*)d_in[0];
    const int*   ei  = (const int*)d_in[1];
    const float* ew  = (const float*)d_in[2];
    const float* W1  = (const float*)d_in[3];
    const float* b1  = (const float*)d_in[4];
    const float* W2  = (const float*)d_in[5];
    const float* b2  = (const float*)d_in[6];
    float* out = (float*)d_out;

    const int N = in_sizes[0] / 256;   // 100000
    const int E = in_sizes[2];         // 1600000
    const int* src = ei;
    const int* dst = ei + E;
    const int NBUCK = (N + 127) >> 7;  // 782
    const int EPB = (E + NSLAB - 1) / NSLAB;

    char* ws = (char*)d_ws;
    size_t off = 0;
    auto take = [&](size_t bytes) -> void* {
        void* p = (void*)(ws + off);
        off += (bytes + 255) & ~(size_t)255;
        return p;
    };
    int*   cnt1    = (int*)take((size_t)NSLAB * NBUCK * 4);   // 1.2MB
    int*   colTot  = (int*)take((size_t)NBUCK * 4);
    int*   bucketBase = (int*)take((size_t)(NBUCK + 1) * 4);
    int*   rowp    = (int*)take((size_t)(N + 1) * 4);
    float* dinv    = (float*)take((size_t)N * 4);
    u64*   tmp     = (u64*)take((size_t)E * 8);               // 12.8MB (packed)
    int2*  entries = (int2*)take((size_t)E * 8);              // 12.8MB
    u16*   wt_hi   = (u16*)take((size_t)128 * 256 * 2);
    u16*   xw1     = (u16*)take((size_t)N * 128 * 2);
    u16*   agg1    = (u16*)take((size_t)N * 128 * 2);         // bf16
    u16*   hw2     = (u16*)take((size_t)N * HW2S * 2);        // 12.8MB

    k_wsplit<<<(256 * 128 + 255) / 256, 256, 0, stream>>>(W1, wt_hi);
    k_count<<<NSLAB, 256, 0, stream>>>(dst, cnt1, E, EPB, NBUCK);
    k_s2a<<<NBUCK, NSLAB, 0, stream>>>(cnt1, colTot, NBUCK);
    k_s2b<<<1, 1024, 0, stream>>>(colTot, bucketBase, rowp, NBUCK, N, E);

    const int gB = (N + 127) / 128;           // 782 gemm tiles
    k_fat<<<gB + NSLAB, 256, 0, stream>>>(x, wt_hi, xw1, N,
                                          src, dst, ew, cnt1, bucketBase, tmp,
                                          E, gB, EPB, NBUCK);

    k_s4<<<NBUCK, 256, 0, stream>>>(tmp, bucketBase, rowp, dinv, entries, N);

    k_gather1<<<((size_t)N * 32 + 255) / 256, 256, 0, stream>>>(xw1, entries, rowp, dinv, agg1, N);
    k_gemm2<<<(N + 63) / 64, 320, 0, stream>>>(agg1, W2, b1, dinv, hw2, N);
    k_gather2<<<(N * 8 + 255) / 256, 256, 0, stream>>>(hw2, entries, rowp, dinv, b2, out, N);
}